// Round 2
// baseline (2396.486 us; speedup 1.0000x reference)
//
#include <hip/hip_runtime.h>

#define N_NODES 100000
#define N_EDGES 1600000
#define IN_F 128
#define HID 128
#define OUTF 64

typedef unsigned int uint;
typedef unsigned short ushort;

__device__ __forceinline__ float bf2f(ushort u) {
  return __uint_as_float(((uint)u) << 16);
}
__device__ __forceinline__ ushort f2bf(float f) {
  uint x = __float_as_uint(f);
  x += 0x7fffu + ((x >> 16) & 1u);  // round-to-nearest-even
  return (ushort)(x >> 16);
}
__device__ __forceinline__ float2 bfpair(uint u) {
  float2 r;
  r.x = __uint_as_float(u << 16);
  r.y = __uint_as_float(u & 0xffff0000u);
  return r;
}

#define BF8_TO_F(dstv, u4)                                     \
  {                                                            \
    float2 _p0 = bfpair((u4).x), _p1 = bfpair((u4).y);         \
    float2 _p2 = bfpair((u4).z), _p3 = bfpair((u4).w);         \
    dstv[0] = _p0.x; dstv[1] = _p0.y;                          \
    dstv[2] = _p1.x; dstv[3] = _p1.y;                          \
    dstv[4] = _p2.x; dstv[5] = _p2.y;                          \
    dstv[6] = _p3.x; dstv[7] = _p3.y;                          \
  }

// ---------------- Layer 0 edge scatter: agg0 += feat[src], deg += 1 --------
// One wave per edge; lane handles 2 f32 feats (float2 8B coalesced read of
// the 512B source row), 2 fp32 atomicAdds into the destination row.
__global__ __launch_bounds__(256) void k_scatter0(
    const float* __restrict__ feat, const int* __restrict__ src,
    const int* __restrict__ dst, float* __restrict__ agg,
    float* __restrict__ deg) {
  int wid = blockIdx.x * 4 + (threadIdx.x >> 6);
  int lane = threadIdx.x & 63;
  if (wid >= N_EDGES) return;
  int s = src[wid];
  int d = dst[wid];
  float2 v = reinterpret_cast<const float2*>(feat + (size_t)s * IN_F)[lane];
  float* a = agg + (size_t)d * IN_F + lane * 2;
  atomicAdd(a, v.x);
  atomicAdd(a + 1, v.y);
  if (lane == 0) atomicAdd(deg + d, 1.0f);
}

// ---------------- Layer 0 GEMM: h = relu(feat@Ws0 + (agg0/deg)@Wn0 + b0) ---
// Block = 256 threads = 16 rows x 16 col-groups (8 outputs each).
// Rows staged to LDS (pad +4 floats). Weights (64KB each, L2-resident)
// streamed as float4. h stored as bf16 (halves layer-1 traffic; rounding
// ~0.2% << 2% threshold).
__global__ __launch_bounds__(256) void k_gemm0(
    const float* __restrict__ feat, const float* __restrict__ agg,
    const float* __restrict__ deg, const float* __restrict__ Ws,
    const float* __restrict__ Wn, const float* __restrict__ bias,
    ushort* __restrict__ h) {
  __shared__ float xs[16][IN_F + 4];
  __shared__ float as[16][IN_F + 4];
  int t = threadIdx.x;
  int rl = t >> 4;
  int k0 = (t & 15) * 8;
  int r = blockIdx.x * 16 + rl;

  float inv = 1.0f / fmaxf(deg[r], 1.0f);
  float4 f0 = *reinterpret_cast<const float4*>(feat + (size_t)r * IN_F + k0);
  float4 f1 = *reinterpret_cast<const float4*>(feat + (size_t)r * IN_F + k0 + 4);
  float4 a0 = *reinterpret_cast<const float4*>(agg + (size_t)r * IN_F + k0);
  float4 a1 = *reinterpret_cast<const float4*>(agg + (size_t)r * IN_F + k0 + 4);
  xs[rl][k0 + 0] = f0.x; xs[rl][k0 + 1] = f0.y;
  xs[rl][k0 + 2] = f0.z; xs[rl][k0 + 3] = f0.w;
  xs[rl][k0 + 4] = f1.x; xs[rl][k0 + 5] = f1.y;
  xs[rl][k0 + 6] = f1.z; xs[rl][k0 + 7] = f1.w;
  as[rl][k0 + 0] = a0.x * inv; as[rl][k0 + 1] = a0.y * inv;
  as[rl][k0 + 2] = a0.z * inv; as[rl][k0 + 3] = a0.w * inv;
  as[rl][k0 + 4] = a1.x * inv; as[rl][k0 + 5] = a1.y * inv;
  as[rl][k0 + 6] = a1.z * inv; as[rl][k0 + 7] = a1.w * inv;
  __syncthreads();

  int j0 = (t & 15) * 8;
  float acc[8];
#pragma unroll
  for (int i = 0; i < 8; ++i) acc[i] = bias[j0 + i];

#pragma unroll 8
  for (int k = 0; k < IN_F; ++k) {
    float x = xs[rl][k];
    float aa = as[rl][k];
    float4 w0 = *reinterpret_cast<const float4*>(Ws + k * HID + j0);
    float4 w1 = *reinterpret_cast<const float4*>(Ws + k * HID + j0 + 4);
    float4 n0 = *reinterpret_cast<const float4*>(Wn + k * HID + j0);
    float4 n1 = *reinterpret_cast<const float4*>(Wn + k * HID + j0 + 4);
    acc[0] += x * w0.x + aa * n0.x;
    acc[1] += x * w0.y + aa * n0.y;
    acc[2] += x * w0.z + aa * n0.z;
    acc[3] += x * w0.w + aa * n0.w;
    acc[4] += x * w1.x + aa * n1.x;
    acc[5] += x * w1.y + aa * n1.y;
    acc[6] += x * w1.z + aa * n1.z;
    acc[7] += x * w1.w + aa * n1.w;
  }

  uint4 o;
  o.x = (uint)f2bf(fmaxf(acc[0], 0.f)) | ((uint)f2bf(fmaxf(acc[1], 0.f)) << 16);
  o.y = (uint)f2bf(fmaxf(acc[2], 0.f)) | ((uint)f2bf(fmaxf(acc[3], 0.f)) << 16);
  o.z = (uint)f2bf(fmaxf(acc[4], 0.f)) | ((uint)f2bf(fmaxf(acc[5], 0.f)) << 16);
  o.w = (uint)f2bf(fmaxf(acc[6], 0.f)) | ((uint)f2bf(fmaxf(acc[7], 0.f)) << 16);
  *reinterpret_cast<uint4*>(h + (size_t)r * HID + j0) = o;
}

// ---------------- hw = h @ Wn1  (N x 64, bf16 out) -------------------------
// Linearity: mean_agg(h) @ Wn1 == mean_agg(h @ Wn1). Doing the GEMM first
// halves layer-1 edge gather traffic (64 bf16/edge instead of 128).
__global__ __launch_bounds__(256) void k_gemm_nw1(
    const ushort* __restrict__ h, const float* __restrict__ Wn,
    ushort* __restrict__ hw) {
  __shared__ float xs[32][HID + 4];
  int t = threadIdx.x;
  int rl = t >> 3;         // 0..31
  int k0 = (t & 7) * 16;   // 0..112
  int r = blockIdx.x * 32 + rl;

  uint4 u0 = *reinterpret_cast<const uint4*>(h + (size_t)r * HID + k0);
  uint4 u1 = *reinterpret_cast<const uint4*>(h + (size_t)r * HID + k0 + 8);
  float v0[8], v1[8];
  BF8_TO_F(v0, u0);
  BF8_TO_F(v1, u1);
#pragma unroll
  for (int i = 0; i < 8; ++i) {
    xs[rl][k0 + i] = v0[i];
    xs[rl][k0 + 8 + i] = v1[i];
  }
  __syncthreads();

  int j0 = (t & 7) * 8;
  float acc[8];
#pragma unroll
  for (int i = 0; i < 8; ++i) acc[i] = 0.f;

#pragma unroll 8
  for (int k = 0; k < HID; ++k) {
    float x = xs[rl][k];
    float4 w0 = *reinterpret_cast<const float4*>(Wn + k * OUTF + j0);
    float4 w1 = *reinterpret_cast<const float4*>(Wn + k * OUTF + j0 + 4);
    acc[0] += x * w0.x; acc[1] += x * w0.y;
    acc[2] += x * w0.z; acc[3] += x * w0.w;
    acc[4] += x * w1.x; acc[5] += x * w1.y;
    acc[6] += x * w1.z; acc[7] += x * w1.w;
  }

  uint4 o;
  o.x = (uint)f2bf(acc[0]) | ((uint)f2bf(acc[1]) << 16);
  o.y = (uint)f2bf(acc[2]) | ((uint)f2bf(acc[3]) << 16);
  o.z = (uint)f2bf(acc[4]) | ((uint)f2bf(acc[5]) << 16);
  o.w = (uint)f2bf(acc[6]) | ((uint)f2bf(acc[7]) << 16);
  *reinterpret_cast<uint4*>(hw + (size_t)r * OUTF + j0) = o;
}

// ---------------- Layer 1 edge scatter: agg1 += hw[src] --------------------
__global__ __launch_bounds__(256) void k_scatter1(
    const ushort* __restrict__ hw, const int* __restrict__ src,
    const int* __restrict__ dst, float* __restrict__ agg) {
  int wid = blockIdx.x * 4 + (threadIdx.x >> 6);
  int lane = threadIdx.x & 63;
  if (wid >= N_EDGES) return;
  int s = src[wid];
  int d = dst[wid];
  float v = bf2f(hw[(size_t)s * OUTF + lane]);
  atomicAdd(agg + (size_t)d * OUTF + lane, v);
}

// ---------------- out = h @ Ws1 + agg1/deg + b1  (f32 out) -----------------
__global__ __launch_bounds__(256) void k_gemm_out(
    const ushort* __restrict__ h, const float* __restrict__ agg,
    const float* __restrict__ deg, const float* __restrict__ Ws,
    const float* __restrict__ bias, float* __restrict__ out) {
  __shared__ float xs[32][HID + 4];
  int t = threadIdx.x;
  int rl = t >> 3;
  int k0 = (t & 7) * 16;
  int r = blockIdx.x * 32 + rl;

  uint4 u0 = *reinterpret_cast<const uint4*>(h + (size_t)r * HID + k0);
  uint4 u1 = *reinterpret_cast<const uint4*>(h + (size_t)r * HID + k0 + 8);
  float v0[8], v1[8];
  BF8_TO_F(v0, u0);
  BF8_TO_F(v1, u1);
#pragma unroll
  for (int i = 0; i < 8; ++i) {
    xs[rl][k0 + i] = v0[i];
    xs[rl][k0 + 8 + i] = v1[i];
  }
  __syncthreads();

  int j0 = (t & 7) * 8;
  float inv = 1.0f / fmaxf(deg[r], 1.0f);
  float4 g0 = *reinterpret_cast<const float4*>(agg + (size_t)r * OUTF + j0);
  float4 g1 = *reinterpret_cast<const float4*>(agg + (size_t)r * OUTF + j0 + 4);
  float acc[8];
  acc[0] = bias[j0 + 0] + g0.x * inv;
  acc[1] = bias[j0 + 1] + g0.y * inv;
  acc[2] = bias[j0 + 2] + g0.z * inv;
  acc[3] = bias[j0 + 3] + g0.w * inv;
  acc[4] = bias[j0 + 4] + g1.x * inv;
  acc[5] = bias[j0 + 5] + g1.y * inv;
  acc[6] = bias[j0 + 6] + g1.z * inv;
  acc[7] = bias[j0 + 7] + g1.w * inv;

#pragma unroll 8
  for (int k = 0; k < HID; ++k) {
    float x = xs[rl][k];
    float4 w0 = *reinterpret_cast<const float4*>(Ws + k * OUTF + j0);
    float4 w1 = *reinterpret_cast<const float4*>(Ws + k * OUTF + j0 + 4);
    acc[0] += x * w0.x; acc[1] += x * w0.y;
    acc[2] += x * w0.z; acc[3] += x * w0.w;
    acc[4] += x * w1.x; acc[5] += x * w1.y;
    acc[6] += x * w1.z; acc[7] += x * w1.w;
  }

  float4 o0 = make_float4(acc[0], acc[1], acc[2], acc[3]);
  float4 o1 = make_float4(acc[4], acc[5], acc[6], acc[7]);
  *reinterpret_cast<float4*>(out + (size_t)r * OUTF + j0) = o0;
  *reinterpret_cast<float4*>(out + (size_t)r * OUTF + j0 + 4) = o1;
}

extern "C" void kernel_launch(void* const* d_in, const int* in_sizes, int n_in,
                              void* d_out, int out_size, void* d_ws,
                              size_t ws_size, hipStream_t stream) {
  const float* feat = (const float*)d_in[0];
  const int* src = (const int*)d_in[1];
  const int* dst = (const int*)d_in[2];
  const float* Ws0 = (const float*)d_in[3];
  const float* Wn0 = (const float*)d_in[4];
  const float* b0 = (const float*)d_in[5];
  const float* Ws1 = (const float*)d_in[6];
  const float* Wn1 = (const float*)d_in[7];
  const float* b1 = (const float*)d_in[8];
  char* ws = (char*)d_ws;

  // Workspace layout (bytes), total 77.2 MB:
  //   h    @ 0          : N*128*2 = 25,600,000  (bf16 hidden, stored by us)
  //   deg  @ 25,600,000 : N*4     =    400,000  (f32 in-degree)
  //   agg0 @ 26,000,000 : N*128*4 = 51,200,000  (f32; region reused below)
  //   hw   @ 26,000,000 : N*64*2  = 12,800,000  (bf16, reuse of agg0)
  //   agg1 @ 38,800,000 : N*64*4  = 25,600,000  (f32, reuse of agg0)
  ushort* h = (ushort*)(ws);
  float* deg = (float*)(ws + 25600000);
  float* agg0 = (float*)(ws + 26000000);
  ushort* hw = (ushort*)(ws + 26000000);
  float* agg1 = (float*)(ws + 38800000);
  float* out = (float*)d_out;

  // zero deg + agg0 (contiguous)
  hipMemsetAsync(ws + 25600000, 0, 400000 + 51200000, stream);
  k_scatter0<<<N_EDGES / 4, 256, 0, stream>>>(feat, src, dst, agg0, deg);
  k_gemm0<<<N_NODES / 16, 256, 0, stream>>>(feat, agg0, deg, Ws0, Wn0, b0, h);
  // agg0 region now dead; carve hw + agg1 out of it
  hipMemsetAsync((char*)agg1, 0, 25600000, stream);
  k_gemm_nw1<<<N_NODES / 32, 256, 0, stream>>>(h, Wn1, hw);
  k_scatter1<<<N_EDGES / 4, 256, 0, stream>>>(hw, src, dst, agg1);
  k_gemm_out<<<N_NODES / 32, 256, 0, stream>>>(h, agg1, deg, Ws1, b1, out);
}

// Round 3
// 986.829 us; speedup vs baseline: 2.4285x; 2.4285x over previous
//
#include <hip/hip_runtime.h>

#define N_NODES 100000
#define N_EDGES 1600000
#define IN_F 128
#define HID 128
#define OUTF 64
#define CAP 56        // bucket capacity per node; Poisson(16) tail -> P(deg>56) ~ 1e-15
#define OVF_CAP 8192  // correctness fallback for pathological degrees

typedef unsigned int uint;
typedef unsigned short ushort;

__device__ __forceinline__ float bf2f(ushort u) {
  return __uint_as_float(((uint)u) << 16);
}
__device__ __forceinline__ ushort f2bf(float f) {
  uint x = __float_as_uint(f);
  x += 0x7fffu + ((x >> 16) & 1u);  // round-to-nearest-even
  return (ushort)(x >> 16);
}
__device__ __forceinline__ float2 bfpair(uint u) {
  float2 r;
  r.x = __uint_as_float(u << 16);
  r.y = __uint_as_float(u & 0xffff0000u);
  return r;
}

#define BF8_TO_F(dstv, u4)                                     \
  {                                                            \
    float2 _p0 = bfpair((u4).x), _p1 = bfpair((u4).y);         \
    float2 _p2 = bfpair((u4).z), _p3 = bfpair((u4).w);         \
    dstv[0] = _p0.x; dstv[1] = _p0.y;                          \
    dstv[2] = _p1.x; dstv[3] = _p1.y;                          \
    dstv[4] = _p2.x; dstv[5] = _p2.y;                          \
    dstv[6] = _p3.x; dstv[7] = _p3.y;                          \
  }

// ---------------- Bucket build: counting-sort edges by dst -----------------
// int atomics on 400KB cnt array (L2-resident, ~16-way mean contention).
__global__ __launch_bounds__(256) void k_bucket(
    const int* __restrict__ src, const int* __restrict__ dst,
    int* __restrict__ cnt, int* __restrict__ bucket, int* __restrict__ ovf_cnt,
    int* __restrict__ ovf) {
  int i = blockIdx.x * 256 + threadIdx.x;
  if (i >= N_EDGES) return;
  int s = src[i];
  int d = dst[i];
  int pos = atomicAdd(&cnt[d], 1);
  if (pos < CAP) {
    bucket[(size_t)d * CAP + pos] = s;
  } else {
    int o = atomicAdd(ovf_cnt, 1);
    if (o < OVF_CAP) {
      ovf[2 * o] = s;
      ovf[2 * o + 1] = d;
    }
  }
}

// ---------------- Layer 0 aggregation: agg0[n] = mean(feat[src in-edges]) --
// One wave per node. Broadcast src via shfl; each lane owns 2 feats (float2,
// 8B coalesced -> 512B row per edge). Row written ONCE, no atomics.
// Output stored as bf16 mean (halves gemm0's agg read).
__global__ __launch_bounds__(256) void k_agg0(
    const float* __restrict__ feat, const int* __restrict__ cnt,
    const int* __restrict__ bucket, const int* __restrict__ ovf_cnt,
    const int* __restrict__ ovf, uint* __restrict__ agg0u) {
  int n = blockIdx.x * 4 + (threadIdx.x >> 6);
  int lane = threadIdx.x & 63;
  if (n >= N_NODES) return;
  int c = cnt[n];
  int kb = min(c, CAP);
  int id = (lane < kb) ? bucket[(size_t)n * CAP + lane] : 0;
  float2 acc = make_float2(0.f, 0.f);
  const float2* feat2 = reinterpret_cast<const float2*>(feat);
  for (int j = 0; j < kb; ++j) {
    int s = __shfl(id, j, 64);
    float2 v = feat2[(size_t)s * 64 + lane];
    acc.x += v.x;
    acc.y += v.y;
  }
  // cold correctness path: edges that overflowed the bucket
  int oc = min(*ovf_cnt, OVF_CAP);
  for (int i = 0; i < oc; ++i) {
    if (ovf[2 * i + 1] == n) {
      float2 v = feat2[(size_t)ovf[2 * i] * 64 + lane];
      acc.x += v.x;
      acc.y += v.y;
    }
  }
  float inv = 1.0f / (float)max(c, 1);
  acc.x *= inv;
  acc.y *= inv;
  agg0u[(size_t)n * 64 + lane] = (uint)f2bf(acc.x) | ((uint)f2bf(acc.y) << 16);
}

// ---------------- Layer 0 GEMM: h = relu(feat@Ws0 + agg0@Wn0 + b0) ---------
// agg0 is already the mean (bf16). 16 rows x 16 col-groups per block.
__global__ __launch_bounds__(256) void k_gemm0(
    const float* __restrict__ feat, const uint* __restrict__ agg0u,
    const float* __restrict__ Ws, const float* __restrict__ Wn,
    const float* __restrict__ bias, ushort* __restrict__ h) {
  __shared__ float xs[16][IN_F + 4];
  __shared__ float as[16][IN_F + 4];
  int t = threadIdx.x;
  int rl = t >> 4;
  int k0 = (t & 15) * 8;
  int r = blockIdx.x * 16 + rl;

  float4 f0 = *reinterpret_cast<const float4*>(feat + (size_t)r * IN_F + k0);
  float4 f1 = *reinterpret_cast<const float4*>(feat + (size_t)r * IN_F + k0 + 4);
  uint4 au = *reinterpret_cast<const uint4*>(agg0u + (size_t)r * 64 + (k0 >> 1));
  float av[8];
  BF8_TO_F(av, au);
  xs[rl][k0 + 0] = f0.x; xs[rl][k0 + 1] = f0.y;
  xs[rl][k0 + 2] = f0.z; xs[rl][k0 + 3] = f0.w;
  xs[rl][k0 + 4] = f1.x; xs[rl][k0 + 5] = f1.y;
  xs[rl][k0 + 6] = f1.z; xs[rl][k0 + 7] = f1.w;
#pragma unroll
  for (int i = 0; i < 8; ++i) as[rl][k0 + i] = av[i];
  __syncthreads();

  int j0 = (t & 15) * 8;
  float acc[8];
#pragma unroll
  for (int i = 0; i < 8; ++i) acc[i] = bias[j0 + i];

#pragma unroll 8
  for (int k = 0; k < IN_F; ++k) {
    float x = xs[rl][k];
    float aa = as[rl][k];
    float4 w0 = *reinterpret_cast<const float4*>(Ws + k * HID + j0);
    float4 w1 = *reinterpret_cast<const float4*>(Ws + k * HID + j0 + 4);
    float4 n0 = *reinterpret_cast<const float4*>(Wn + k * HID + j0);
    float4 n1 = *reinterpret_cast<const float4*>(Wn + k * HID + j0 + 4);
    acc[0] += x * w0.x + aa * n0.x;
    acc[1] += x * w0.y + aa * n0.y;
    acc[2] += x * w0.z + aa * n0.z;
    acc[3] += x * w0.w + aa * n0.w;
    acc[4] += x * w1.x + aa * n1.x;
    acc[5] += x * w1.y + aa * n1.y;
    acc[6] += x * w1.z + aa * n1.z;
    acc[7] += x * w1.w + aa * n1.w;
  }

  uint4 o;
  o.x = (uint)f2bf(fmaxf(acc[0], 0.f)) | ((uint)f2bf(fmaxf(acc[1], 0.f)) << 16);
  o.y = (uint)f2bf(fmaxf(acc[2], 0.f)) | ((uint)f2bf(fmaxf(acc[3], 0.f)) << 16);
  o.z = (uint)f2bf(fmaxf(acc[4], 0.f)) | ((uint)f2bf(fmaxf(acc[5], 0.f)) << 16);
  o.w = (uint)f2bf(fmaxf(acc[6], 0.f)) | ((uint)f2bf(fmaxf(acc[7], 0.f)) << 16);
  *reinterpret_cast<uint4*>(h + (size_t)r * HID + j0) = o;
}

// ---------------- hw = h @ Wn1  (N x 64, bf16 out) -------------------------
// Linearity: mean_agg(h) @ Wn1 == mean_agg(h @ Wn1); halves L1 gather bytes.
__global__ __launch_bounds__(256) void k_gemm_nw1(
    const ushort* __restrict__ h, const float* __restrict__ Wn,
    ushort* __restrict__ hw) {
  __shared__ float xs[32][HID + 4];
  int t = threadIdx.x;
  int rl = t >> 3;
  int k0 = (t & 7) * 16;
  int r = blockIdx.x * 32 + rl;

  uint4 u0 = *reinterpret_cast<const uint4*>(h + (size_t)r * HID + k0);
  uint4 u1 = *reinterpret_cast<const uint4*>(h + (size_t)r * HID + k0 + 8);
  float v0[8], v1[8];
  BF8_TO_F(v0, u0);
  BF8_TO_F(v1, u1);
#pragma unroll
  for (int i = 0; i < 8; ++i) {
    xs[rl][k0 + i] = v0[i];
    xs[rl][k0 + 8 + i] = v1[i];
  }
  __syncthreads();

  int j0 = (t & 7) * 8;
  float acc[8];
#pragma unroll
  for (int i = 0; i < 8; ++i) acc[i] = 0.f;

#pragma unroll 8
  for (int k = 0; k < HID; ++k) {
    float x = xs[rl][k];
    float4 w0 = *reinterpret_cast<const float4*>(Wn + k * OUTF + j0);
    float4 w1 = *reinterpret_cast<const float4*>(Wn + k * OUTF + j0 + 4);
    acc[0] += x * w0.x; acc[1] += x * w0.y;
    acc[2] += x * w0.z; acc[3] += x * w0.w;
    acc[4] += x * w1.x; acc[5] += x * w1.y;
    acc[6] += x * w1.z; acc[7] += x * w1.w;
  }

  uint4 o;
  o.x = (uint)f2bf(acc[0]) | ((uint)f2bf(acc[1]) << 16);
  o.y = (uint)f2bf(acc[2]) | ((uint)f2bf(acc[3]) << 16);
  o.z = (uint)f2bf(acc[4]) | ((uint)f2bf(acc[5]) << 16);
  o.w = (uint)f2bf(acc[6]) | ((uint)f2bf(acc[7]) << 16);
  *reinterpret_cast<uint4*>(hw + (size_t)r * OUTF + j0) = o;
}

// ---------------- Layer 1 aggregation: out[n] = mean(hw[src in-edges]) -----
// One wave per node, 2 edges per iteration (row = 128B = 32 uints; lanes
// 0-31 -> edge j, lanes 32-63 -> edge j+1), halves combined via shfl_xor.
// Writes f32 mean directly into d_out (gemm_out reads+overwrites in place).
__global__ __launch_bounds__(256) void k_agg1(
    const uint* __restrict__ hwu, const int* __restrict__ cnt,
    const int* __restrict__ bucket, const int* __restrict__ ovf_cnt,
    const int* __restrict__ ovf, float* __restrict__ out) {
  int n = blockIdx.x * 4 + (threadIdx.x >> 6);
  int lane = threadIdx.x & 63;
  if (n >= N_NODES) return;
  int half = lane >> 5;
  int li = lane & 31;
  int c = cnt[n];
  int kb = min(c, CAP);
  int id = (lane < kb) ? bucket[(size_t)n * CAP + lane] : 0;
  float2 acc = make_float2(0.f, 0.f);
  for (int j = 0; j < kb; j += 2) {
    int jj = j + half;
    int s = __shfl(id, jj, 64);
    if (jj < kb) {
      float2 v = bfpair(hwu[(size_t)s * 32 + li]);
      acc.x += v.x;
      acc.y += v.y;
    }
  }
  // cold overflow path (lower half only; upper half contributes 0)
  int oc = min(*ovf_cnt, OVF_CAP);
  for (int i = 0; i < oc; ++i) {
    if (half == 0 && ovf[2 * i + 1] == n) {
      float2 v = bfpair(hwu[(size_t)ovf[2 * i] * 32 + li]);
      acc.x += v.x;
      acc.y += v.y;
    }
  }
  acc.x += __shfl_xor(acc.x, 32, 64);
  acc.y += __shfl_xor(acc.y, 32, 64);
  if (half == 0) {
    float inv = 1.0f / (float)max(c, 1);
    float2 m = make_float2(acc.x * inv, acc.y * inv);
    *reinterpret_cast<float2*>(out + (size_t)n * OUTF + li * 2) = m;
  }
}

// ---------------- out = h @ Ws1 + out(=mean agg1) + b1  (f32, in place) ----
__global__ __launch_bounds__(256) void k_gemm_out(
    const ushort* __restrict__ h, const float* __restrict__ Ws,
    const float* __restrict__ bias, float* __restrict__ out) {
  __shared__ float xs[32][HID + 4];
  int t = threadIdx.x;
  int rl = t >> 3;
  int k0 = (t & 7) * 16;
  int r = blockIdx.x * 32 + rl;

  uint4 u0 = *reinterpret_cast<const uint4*>(h + (size_t)r * HID + k0);
  uint4 u1 = *reinterpret_cast<const uint4*>(h + (size_t)r * HID + k0 + 8);
  float v0[8], v1[8];
  BF8_TO_F(v0, u0);
  BF8_TO_F(v1, u1);
#pragma unroll
  for (int i = 0; i < 8; ++i) {
    xs[rl][k0 + i] = v0[i];
    xs[rl][k0 + 8 + i] = v1[i];
  }
  __syncthreads();

  int j0 = (t & 7) * 8;
  float4 g0 = *reinterpret_cast<const float4*>(out + (size_t)r * OUTF + j0);
  float4 g1 = *reinterpret_cast<const float4*>(out + (size_t)r * OUTF + j0 + 4);
  float acc[8];
  acc[0] = bias[j0 + 0] + g0.x;
  acc[1] = bias[j0 + 1] + g0.y;
  acc[2] = bias[j0 + 2] + g0.z;
  acc[3] = bias[j0 + 3] + g0.w;
  acc[4] = bias[j0 + 4] + g1.x;
  acc[5] = bias[j0 + 5] + g1.y;
  acc[6] = bias[j0 + 6] + g1.z;
  acc[7] = bias[j0 + 7] + g1.w;

#pragma unroll 8
  for (int k = 0; k < HID; ++k) {
    float x = xs[rl][k];
    float4 w0 = *reinterpret_cast<const float4*>(Ws + k * OUTF + j0);
    float4 w1 = *reinterpret_cast<const float4*>(Ws + k * OUTF + j0 + 4);
    acc[0] += x * w0.x; acc[1] += x * w0.y;
    acc[2] += x * w0.z; acc[3] += x * w0.w;
    acc[4] += x * w1.x; acc[5] += x * w1.y;
    acc[6] += x * w1.z; acc[7] += x * w1.w;
  }

  *reinterpret_cast<float4*>(out + (size_t)r * OUTF + j0) =
      make_float4(acc[0], acc[1], acc[2], acc[3]);
  *reinterpret_cast<float4*>(out + (size_t)r * OUTF + j0 + 4) =
      make_float4(acc[4], acc[5], acc[6], acc[7]);
}

extern "C" void kernel_launch(void* const* d_in, const int* in_sizes, int n_in,
                              void* d_out, int out_size, void* d_ws,
                              size_t ws_size, hipStream_t stream) {
  const float* feat = (const float*)d_in[0];
  const int* src = (const int*)d_in[1];
  const int* dst = (const int*)d_in[2];
  const float* Ws0 = (const float*)d_in[3];
  const float* Wn0 = (const float*)d_in[4];
  const float* b0 = (const float*)d_in[5];
  const float* Ws1 = (const float*)d_in[6];
  const float* Wn1 = (const float*)d_in[7];
  const float* b1 = (const float*)d_in[8];
  char* ws = (char*)d_ws;

  // Workspace layout (bytes), total 74.07 MB (<= 77.2 MB proven available):
  //   h       @ 0          : N*128*2      = 25,600,000  (bf16 hidden)
  //   cnt     @ 25,600,000 : N*4          =    400,000  (int in-degree)
  //   ovf_cnt @ 26,000,000 : 64
  //   ovf     @ 26,000,064 : 8192*8       =     65,536
  //   bucket  @ 26,065,600 : N*CAP*4      = 22,400,000
  //   agg0    @ 48,465,600 : N*128*2      = 25,600,000  (bf16 mean)
  //   hw      @ 48,465,600 : N*64*2       = 12,800,000  (bf16, reuses agg0)
  //   agg1    -> lives in d_out (f32 mean, read+overwritten by k_gemm_out)
  ushort* h = (ushort*)(ws);
  int* cnt = (int*)(ws + 25600000);
  int* ovf_cnt = (int*)(ws + 26000000);
  int* ovf = (int*)(ws + 26000064);
  int* bucket = (int*)(ws + 26065600);
  uint* agg0u = (uint*)(ws + 48465600);
  ushort* hw = (ushort*)(ws + 48465600);
  float* out = (float*)d_out;

  // zero cnt + ovf_cnt + ovf (contiguous region)
  hipMemsetAsync(ws + 25600000, 0, 465600, stream);
  k_bucket<<<N_EDGES / 256, 256, 0, stream>>>(src, dst, cnt, bucket, ovf_cnt,
                                              ovf);
  k_agg0<<<N_NODES / 4, 256, 0, stream>>>(feat, cnt, bucket, ovf_cnt, ovf,
                                          agg0u);
  k_gemm0<<<N_NODES / 16, 256, 0, stream>>>(feat, agg0u, Ws0, Wn0, b0, h);
  // agg0 dead from here; hw reuses its region
  k_gemm_nw1<<<N_NODES / 32, 256, 0, stream>>>(h, Wn1, hw);
  k_agg1<<<N_NODES / 4, 256, 0, stream>>>((const uint*)hw, cnt, bucket,
                                          ovf_cnt, ovf, out);
  k_gemm_out<<<N_NODES / 32, 256, 0, stream>>>(h, Ws1, b1, out);
}

// Round 4
// 465.458 us; speedup vs baseline: 5.1487x; 2.1201x over previous
//
#include <hip/hip_runtime.h>

#define N_NODES 100000
#define N_EDGES 1600000
#define IN_F 128
#define HID 128
#define OUTF 64
#define CAP 56        // bucket capacity; Poisson(16) tail beyond 56 ~ never, ovf list covers it
#define OVF_CAP 8192
#define GBLK 782      // ceil(100000/128) gemm blocks

typedef unsigned int uint;
typedef unsigned short ushort;
typedef __attribute__((ext_vector_type(8))) short short8;  // 8 bf16 (4 VGPRs)
typedef __attribute__((ext_vector_type(4))) float f32x4;   // 4 fp32 acc

__device__ __forceinline__ ushort f2bf(float f) {
  uint x = __float_as_uint(f);
  x += 0x7fffu + ((x >> 16) & 1u);  // round-to-nearest-even
  return (ushort)(x >> 16);
}
__device__ __forceinline__ float2 bfpair(uint u) {
  float2 r;
  r.x = __uint_as_float(u << 16);
  r.y = __uint_as_float(u & 0xffff0000u);
  return r;
}

// ---------------- prep: feat f32 -> bf16 (halves gather + feeds MFMA) ------
__global__ __launch_bounds__(256) void k_prep_feat(
    const float* __restrict__ feat, uint* __restrict__ fbfu) {
  int i = blockIdx.x * 256 + threadIdx.x;  // over N*64 uint outputs
  float2 v = reinterpret_cast<const float2*>(feat)[i];
  fbfu[i] = (uint)f2bf(v.x) | ((uint)f2bf(v.y) << 16);
}

// ---------------- prep: pack weights into MFMA B-fragment order ------------
// B-frag layout (16x16x32 bf16, verified m89/m91/m120):
//   lane holds B[k = (lane>>4)*8 + j][n = lane&15], j=0..7 contiguous.
// Wp[( s*8 + t)*64 + lane)*8 + j] = W[32s + 8q + j][16t + c], lane = 16q + c.
// Wp0 = [Ws0; Wn0] (K=256, N=128); Wp1 = [Wn1 | Ws1] (K=128, N=128).
__global__ __launch_bounds__(256) void k_prep_w(
    const float* __restrict__ Ws0, const float* __restrict__ Wn0,
    const float* __restrict__ Ws1, const float* __restrict__ Wn1,
    ushort* __restrict__ wp0, ushort* __restrict__ wp1) {
  int idx = blockIdx.x * 256 + threadIdx.x;  // 49152 = 32768 + 16384
  if (idx < 32768) {
    int k = idx >> 7, n = idx & 127;
    float v = (k < 128) ? Ws0[k * 128 + n] : Wn0[(k - 128) * 128 + n];
    int s = k >> 5, q = (k >> 3) & 3, j = k & 7;
    int t = n >> 4, c = n & 15;
    wp0[(((s * 8 + t) * 64) + (q * 16 + c)) * 8 + j] = f2bf(v);
  } else {
    int i2 = idx - 32768;
    int k = i2 >> 7, n = i2 & 127;
    float v = (n < 64) ? Wn1[k * 64 + n] : Ws1[k * 64 + (n - 64)];
    int s = k >> 5, q = (k >> 3) & 3, j = k & 7;
    int t = n >> 4, c = n & 15;
    wp1[(((s * 8 + t) * 64) + (q * 16 + c)) * 8 + j] = f2bf(v);
  }
}

// ---------------- bucket build: counting-sort edges by dst -----------------
__global__ __launch_bounds__(256) void k_bucket(
    const int* __restrict__ src, const int* __restrict__ dst,
    int* __restrict__ cnt, int* __restrict__ bucket, int* __restrict__ ovf_cnt,
    int* __restrict__ ovf) {
  int i = blockIdx.x * 256 + threadIdx.x;
  if (i >= N_EDGES) return;
  int s = src[i];
  int d = dst[i];
  int pos = atomicAdd(&cnt[d], 1);
  if (pos < CAP) {
    bucket[(size_t)d * CAP + pos] = s;
  } else {
    int o = atomicAdd(ovf_cnt, 1);
    if (o < OVF_CAP) {
      ovf[2 * o] = s;
      ovf[2 * o + 1] = d;
    }
  }
}

// ---------------- layer-0 aggregation: agg0[n] = mean(feat_bf[src]) --------
// One wave/node; lane reads 1 uint (2 bf16) of the 256B bf16 row. No atomics.
__global__ __launch_bounds__(256) void k_agg0(
    const uint* __restrict__ fbfu, const int* __restrict__ cnt,
    const int* __restrict__ bucket, const int* __restrict__ ovf_cnt,
    const int* __restrict__ ovf, uint* __restrict__ aggu) {
  int n = blockIdx.x * 4 + (threadIdx.x >> 6);
  int lane = threadIdx.x & 63;
  if (n >= N_NODES) return;
  int c = cnt[n];
  int kb = min(c, CAP);
  int id = (lane < kb) ? bucket[(size_t)n * CAP + lane] : 0;
  float2 acc = make_float2(0.f, 0.f);
  for (int j = 0; j < kb; ++j) {
    int s = __shfl(id, j, 64);
    float2 v = bfpair(fbfu[(size_t)s * 64 + lane]);
    acc.x += v.x;
    acc.y += v.y;
  }
  int oc = min(*ovf_cnt, OVF_CAP);
  for (int i = 0; i < oc; ++i) {
    if (ovf[2 * i + 1] == n) {
      float2 v = bfpair(fbfu[(size_t)ovf[2 * i] * 64 + lane]);
      acc.x += v.x;
      acc.y += v.y;
    }
  }
  float inv = 1.0f / (float)max(c, 1);
  aggu[(size_t)n * 64 + lane] = (uint)f2bf(acc.x * inv) |
                                ((uint)f2bf(acc.y * inv) << 16);
}

// ---------------- layer-0 MFMA GEMM: h = relu([feat|agg] @ Wp0 + b0) -------
// Block: 128 rows x 128 cols, 4 waves (w>>1 = row-half, w&1 = col-half).
// Wave: 64 rows x 64 cols = 4x4 C-frags; K=256 = 8 mfma steps.
// A-frags from global bf16 (one dwordx4 each); B-frags from LDS (64KB Wp0,
// staged once, no barriers in K-loop). NOTE: aggb and h ALIAS (same buffer,
// block reads own rows then overwrites post-barrier) -- no __restrict__.
__global__ __launch_bounds__(256) void k_gemm0(
    const ushort* __restrict__ fbf, const ushort* aggb,
    const uint4* __restrict__ wp0g, const float* __restrict__ b0,
    ushort* h) {
  __shared__ uint4 wlds[4096];  // 64KB
  int tid = threadIdx.x;
#pragma unroll
  for (int i = 0; i < 16; ++i) wlds[i * 256 + tid] = wp0g[i * 256 + tid];
  __syncthreads();
  const short8* wl8 = reinterpret_cast<const short8*>(wlds);

  int lane = tid & 63, w = tid >> 6;
  int quad = lane >> 4, lm = lane & 15;
  int mw = blockIdx.x * 128 + (w >> 1) * 64;
  int tgb = (w & 1) * 4;

  f32x4 acc[4][4];
#pragma unroll
  for (int rt = 0; rt < 4; ++rt)
#pragma unroll
    for (int ct = 0; ct < 4; ++ct) acc[rt][ct] = (f32x4){0.f, 0.f, 0.f, 0.f};
  short8 az = {0, 0, 0, 0, 0, 0, 0, 0};

#pragma unroll
  for (int s = 0; s < 8; ++s) {
    const ushort* bsrc = (s < 4) ? fbf : aggb;
    int koff = (s & 3) * 32 + quad * 8;
    short8 a[4];
#pragma unroll
    for (int rt = 0; rt < 4; ++rt) {
      int row = mw + rt * 16 + lm;
      a[rt] = (row < N_NODES)
                  ? *reinterpret_cast<const short8*>(bsrc + (size_t)row * 128 + koff)
                  : az;
    }
#pragma unroll
    for (int ct = 0; ct < 4; ++ct) {
      short8 b = wl8[(s * 8 + tgb + ct) * 64 + lane];
#pragma unroll
      for (int rt = 0; rt < 4; ++rt)
        acc[rt][ct] =
            __builtin_amdgcn_mfma_f32_16x16x32_bf16(a[rt], b, acc[rt][ct], 0, 0, 0);
    }
  }

  __syncthreads();  // all waves done reading aggb rows before h overwrites them
  float bv[4];
#pragma unroll
  for (int ct = 0; ct < 4; ++ct) bv[ct] = b0[(tgb + ct) * 16 + lm];
#pragma unroll
  for (int rt = 0; rt < 4; ++rt)
#pragma unroll
    for (int ct = 0; ct < 4; ++ct)
#pragma unroll
      for (int i = 0; i < 4; ++i) {
        int row = mw + rt * 16 + quad * 4 + i;  // C/D: row=quad*4+reg, col=lane&15
        if (row < N_NODES) {
          int col = (tgb + ct) * 16 + lm;
          h[(size_t)row * 128 + col] = f2bf(fmaxf(acc[rt][ct][i] + bv[ct], 0.f));
        }
      }
}

// ---------------- fused layer-1 MFMA GEMM: [hw | sout] = h @ Wp1 -----------
// Col-half 0 -> hw = h@Wn1 (bf16); col-half 1 -> d_out = h@Ws1 + b1 (f32).
// agg1 later ADDS the neighbor mean into d_out in place.
__global__ __launch_bounds__(256) void k_gemm1(
    const ushort* __restrict__ h, const uint4* __restrict__ wp1g,
    const float* __restrict__ b1, ushort* __restrict__ hw,
    float* __restrict__ out) {
  __shared__ uint4 wlds[2048];  // 32KB
  int tid = threadIdx.x;
#pragma unroll
  for (int i = 0; i < 8; ++i) wlds[i * 256 + tid] = wp1g[i * 256 + tid];
  __syncthreads();
  const short8* wl8 = reinterpret_cast<const short8*>(wlds);

  int lane = tid & 63, w = tid >> 6;
  int quad = lane >> 4, lm = lane & 15;
  int mw = blockIdx.x * 128 + (w >> 1) * 64;
  int tgb = (w & 1) * 4;

  f32x4 acc[4][4];
#pragma unroll
  for (int rt = 0; rt < 4; ++rt)
#pragma unroll
    for (int ct = 0; ct < 4; ++ct) acc[rt][ct] = (f32x4){0.f, 0.f, 0.f, 0.f};
  short8 az = {0, 0, 0, 0, 0, 0, 0, 0};

#pragma unroll
  for (int s = 0; s < 4; ++s) {
    int koff = s * 32 + quad * 8;
    short8 a[4];
#pragma unroll
    for (int rt = 0; rt < 4; ++rt) {
      int row = mw + rt * 16 + lm;
      a[rt] = (row < N_NODES)
                  ? *reinterpret_cast<const short8*>(h + (size_t)row * 128 + koff)
                  : az;
    }
#pragma unroll
    for (int ct = 0; ct < 4; ++ct) {
      short8 b = wl8[(s * 8 + tgb + ct) * 64 + lane];
#pragma unroll
      for (int rt = 0; rt < 4; ++rt)
        acc[rt][ct] =
            __builtin_amdgcn_mfma_f32_16x16x32_bf16(a[rt], b, acc[rt][ct], 0, 0, 0);
    }
  }

  if ((w & 1) == 0) {  // cols 0..63 -> hw (bf16)
#pragma unroll
    for (int rt = 0; rt < 4; ++rt)
#pragma unroll
      for (int ct = 0; ct < 4; ++ct)
#pragma unroll
        for (int i = 0; i < 4; ++i) {
          int row = mw + rt * 16 + quad * 4 + i;
          if (row < N_NODES)
            hw[(size_t)row * 64 + ct * 16 + lm] = f2bf(acc[rt][ct][i]);
        }
  } else {  // cols 64..127 -> out = h@Ws1 + b1 (f32)
    float bv[4];
#pragma unroll
    for (int ct = 0; ct < 4; ++ct) bv[ct] = b1[ct * 16 + lm];
#pragma unroll
    for (int rt = 0; rt < 4; ++rt)
#pragma unroll
      for (int ct = 0; ct < 4; ++ct)
#pragma unroll
        for (int i = 0; i < 4; ++i) {
          int row = mw + rt * 16 + quad * 4 + i;
          if (row < N_NODES)
            out[(size_t)row * 64 + ct * 16 + lm] = acc[rt][ct][i] + bv[ct];
        }
  }
}

// ---------------- layer-1 aggregation: out[n] += mean(hw[src]) -------------
// One wave/node, 2 edges/iter (row = 128B = 32 uints). In-place += on d_out.
__global__ __launch_bounds__(256) void k_agg1(
    const uint* __restrict__ hwu, const int* __restrict__ cnt,
    const int* __restrict__ bucket, const int* __restrict__ ovf_cnt,
    const int* __restrict__ ovf, float* __restrict__ out) {
  int n = blockIdx.x * 4 + (threadIdx.x >> 6);
  int lane = threadIdx.x & 63;
  if (n >= N_NODES) return;
  int half = lane >> 5;
  int li = lane & 31;
  int c = cnt[n];
  int kb = min(c, CAP);
  int id = (lane < kb) ? bucket[(size_t)n * CAP + lane] : 0;
  float2 acc = make_float2(0.f, 0.f);
  for (int j = 0; j < kb; j += 2) {
    int jj = j + half;
    int s = __shfl(id, jj, 64);
    if (jj < kb) {
      float2 v = bfpair(hwu[(size_t)s * 32 + li]);
      acc.x += v.x;
      acc.y += v.y;
    }
  }
  int oc = min(*ovf_cnt, OVF_CAP);
  for (int i = 0; i < oc; ++i) {
    if (half == 0 && ovf[2 * i + 1] == n) {
      float2 v = bfpair(hwu[(size_t)ovf[2 * i] * 32 + li]);
      acc.x += v.x;
      acc.y += v.y;
    }
  }
  acc.x += __shfl_xor(acc.x, 32, 64);
  acc.y += __shfl_xor(acc.y, 32, 64);
  if (half == 0) {
    float inv = 1.0f / (float)max(c, 1);
    float2 cur = *reinterpret_cast<float2*>(out + (size_t)n * OUTF + li * 2);
    cur.x += acc.x * inv;
    cur.y += acc.y * inv;
    *reinterpret_cast<float2*>(out + (size_t)n * OUTF + li * 2) = cur;
  }
}

extern "C" void kernel_launch(void* const* d_in, const int* in_sizes, int n_in,
                              void* d_out, int out_size, void* d_ws,
                              size_t ws_size, hipStream_t stream) {
  const float* feat = (const float*)d_in[0];
  const int* src = (const int*)d_in[1];
  const int* dst = (const int*)d_in[2];
  const float* Ws0 = (const float*)d_in[3];
  const float* Wn0 = (const float*)d_in[4];
  const float* b0 = (const float*)d_in[5];
  const float* Ws1 = (const float*)d_in[6];
  const float* Wn1 = (const float*)d_in[7];
  const float* b1 = (const float*)d_in[8];
  char* ws = (char*)d_ws;

  // Workspace (74.16 MB <= 77.2 MB proven):
  //   hbuf    @ 0          : 25,600,000  (bf16 N x 128; agg0 first, then h)
  //   cnt     @ 25,600,000 :    400,000
  //   ovf_cnt @ 26,000,000 :         64
  //   ovf     @ 26,000,064 :     65,536
  //   bucket  @ 26,065,600 : 22,400,000  (CAP=56)
  //   feat_bf @ 48,465,600 : 25,600,000  (bf16 N x 128; hw reuses after gemm0)
  //   wp0     @ 74,065,600 :     65,536  (packed bf16 B-frags, K=256 N=128)
  //   wp1     @ 74,131,136 :     32,768  (packed bf16 B-frags, K=128 N=128)
  ushort* hbuf = (ushort*)(ws);
  int* cnt = (int*)(ws + 25600000);
  int* ovf_cnt = (int*)(ws + 26000000);
  int* ovf = (int*)(ws + 26000064);
  int* bucket = (int*)(ws + 26065600);
  ushort* fbf = (ushort*)(ws + 48465600);
  ushort* hw = (ushort*)(ws + 48465600);  // reuses feat_bf region post-gemm0
  ushort* wp0 = (ushort*)(ws + 74065600);
  ushort* wp1 = (ushort*)(ws + 74131136);
  float* out = (float*)d_out;

  hipMemsetAsync(ws + 25600000, 0, 465600, stream);  // cnt + ovf_cnt + ovf
  k_prep_feat<<<25000, 256, 0, stream>>>(feat, (uint*)fbf);
  k_prep_w<<<192, 256, 0, stream>>>(Ws0, Wn0, Ws1, Wn1, wp0, wp1);
  k_bucket<<<N_EDGES / 256, 256, 0, stream>>>(src, dst, cnt, bucket, ovf_cnt,
                                              ovf);
  k_agg0<<<N_NODES / 4, 256, 0, stream>>>((const uint*)fbf, cnt, bucket,
                                          ovf_cnt, ovf, (uint*)hbuf);
  k_gemm0<<<GBLK, 256, 0, stream>>>(fbf, hbuf, (const uint4*)wp0, b0, hbuf);
  k_gemm1<<<GBLK, 256, 0, stream>>>(hbuf, (const uint4*)wp1, b1, hw, out);
  k_agg1<<<N_NODES / 4, 256, 0, stream>>>((const uint*)hw, cnt, bucket, ovf_cnt,
                                          ovf, out);
}

// Round 5
// 377.008 us; speedup vs baseline: 6.3566x; 1.2346x over previous
//
#include <hip/hip_runtime.h>

#define N_NODES 100000
#define N_EDGES 1600000
#define IN_F 128
#define HID 128
#define OUTF 64
#define CAP 56         // per-node bucket capacity (Poisson(16) tail ~ never)
#define OVF_CAP 8192
#define GBLK 782       // ceil(100000/128) gemm blocks
#define BINS 391       // ceil(100000/256): bin = dst>>8
#define BINCAP 4608    // Poisson(4096) + 8 sigma

typedef unsigned int uint;
typedef unsigned short ushort;
typedef __attribute__((ext_vector_type(8))) short short8;  // 8 bf16 (4 VGPRs)
typedef __attribute__((ext_vector_type(4))) float f32x4;   // 4 fp32 acc

__device__ __forceinline__ ushort f2bf(float f) {
  uint x = __float_as_uint(f);
  x += 0x7fffu + ((x >> 16) & 1u);  // round-to-nearest-even
  return (ushort)(x >> 16);
}
__device__ __forceinline__ float2 bfpair(uint u) {
  float2 r;
  r.x = __uint_as_float(u << 16);
  r.y = __uint_as_float(u & 0xffff0000u);
  return r;
}

// ---------------- fused prep: feat f32->bf16 + weight B-frag packing -------
// B-frag layout (16x16x32 bf16): lane = 16q+c holds B[k=8q+j][n=16t+c].
// Wp0 = [Ws0; Wn0] (K=256, N=128); Wp1 = [Wn1 | Ws1] (K=128, N=128).
__global__ __launch_bounds__(256) void k_prep(
    const float* __restrict__ feat, const float* __restrict__ Ws0,
    const float* __restrict__ Wn0, const float* __restrict__ Ws1,
    const float* __restrict__ Wn1, uint* __restrict__ fbfu,
    ushort* __restrict__ wp0, ushort* __restrict__ wp1) {
  int b = blockIdx.x;
  int tid = threadIdx.x;
  if (b < 25000) {  // feat conversion: N*64 uint outputs
    int i = b * 256 + tid;
    float2 v = reinterpret_cast<const float2*>(feat)[i];
    fbfu[i] = (uint)f2bf(v.x) | ((uint)f2bf(v.y) << 16);
    return;
  }
  int idx = (b - 25000) * 256 + tid;  // 49152 = 32768 + 16384
  if (idx < 32768) {
    int k = idx >> 7, n = idx & 127;
    float v = (k < 128) ? Ws0[k * 128 + n] : Wn0[(k - 128) * 128 + n];
    int s = k >> 5, q = (k >> 3) & 3, j = k & 7;
    int t = n >> 4, c = n & 15;
    wp0[(((s * 8 + t) * 64) + (q * 16 + c)) * 8 + j] = f2bf(v);
  } else {
    int i2 = idx - 32768;
    int k = i2 >> 7, n = i2 & 127;
    float v = (n < 64) ? Wn1[k * 64 + n] : Ws1[k * 64 + (n - 64)];
    int s = k >> 5, q = (k >> 3) & 3, j = k & 7;
    int t = n >> 4, c = n & 15;
    wp1[(((s * 8 + t) * 64) + (q * 16 + c)) * 8 + j] = f2bf(v);
  }
}

// ---------------- bin phase 1: dense per-bin edge segments -----------------
// Block handles 2048 edges: LDS histogram over 391 bins -> reserve contiguous
// ranges with ~391 global atomics -> DENSE packed writes (src | dlow<<17).
__global__ __launch_bounds__(512) void k_bin(
    const int* __restrict__ src, const int* __restrict__ dst,
    uint* __restrict__ gcursor, uint* __restrict__ binbuf,
    int* __restrict__ ovf_cnt, int* __restrict__ ovf, int* __restrict__ cnt) {
  __shared__ uint hist[BINS];
  __shared__ uint base[BINS];
  int tid = threadIdx.x;
  for (int i = tid; i < BINS; i += 512) hist[i] = 0;
  __syncthreads();

  int e0 = blockIdx.x * 2048;
  uint val[4], bin[4], rank[4];
  int valid[4];
#pragma unroll
  for (int it = 0; it < 4; ++it) {
    int e = e0 + it * 512 + tid;
    valid[it] = (e < N_EDGES);
    if (valid[it]) {
      uint s = (uint)src[e];
      uint d = (uint)dst[e];
      bin[it] = d >> 8;
      rank[it] = atomicAdd(&hist[bin[it]], 1u);
      val[it] = s | ((d & 255u) << 17);
    }
  }
  __syncthreads();
  for (int i = tid; i < BINS; i += 512)
    base[i] = hist[i] ? atomicAdd(&gcursor[i], hist[i]) : 0u;
  __syncthreads();

#pragma unroll
  for (int it = 0; it < 4; ++it) {
    if (!valid[it]) continue;
    uint p = base[bin[it]] + rank[it];
    if (p < BINCAP) {
      binbuf[(size_t)bin[it] * BINCAP + p] = val[it];
    } else {  // astronomically rare: binbuf overflow -> ovf list + cnt
      int s = (int)(val[it] & 0x1FFFFu);
      int d = (int)(bin[it] * 256 + (val[it] >> 17));
      int o = atomicAdd(ovf_cnt, 1);
      if (o < OVF_CAP) {
        ovf[2 * o] = s;
        ovf[2 * o + 1] = d;
      }
      atomicAdd(&cnt[d], 1);
    }
  }
}

// ---------------- bin phase 2: exclusive per-bin scatter -------------------
// One block OWNS one bin (256 nodes): LDS position counters (no global
// atomics), bucket writes confined to a private 57KB slice (CU-local L2).
__global__ __launch_bounds__(256) void k_scat(
    const uint* __restrict__ binbuf, const uint* __restrict__ gcursor,
    int* __restrict__ bucket, int* __restrict__ cnt, int* __restrict__ ovf_cnt,
    int* __restrict__ ovf) {
  __shared__ uint lcnt[256];
  int b = blockIdx.x;
  int tid = threadIdx.x;
  lcnt[tid] = 0;
  __syncthreads();
  int ne = min((int)gcursor[b], BINCAP);
  for (int i = tid; i < ne; i += 256) {
    uint v = binbuf[(size_t)b * BINCAP + i];
    int s = (int)(v & 0x1FFFFu);
    uint dl = v >> 17;
    uint pos = atomicAdd(&lcnt[dl], 1u);
    int d = b * 256 + (int)dl;
    if (pos < CAP) {
      bucket[(size_t)d * CAP + pos] = s;
    } else {
      int o = atomicAdd(ovf_cnt, 1);
      if (o < OVF_CAP) {
        ovf[2 * o] = s;
        ovf[2 * o + 1] = d;
      }
    }
  }
  __syncthreads();
  int d = b * 256 + tid;
  if (d < N_NODES && lcnt[tid]) atomicAdd(&cnt[d], (int)lcnt[tid]);
}

// ---------------- layer-0 aggregation: agg0[n] = mean(feat_bf[src]) --------
__global__ __launch_bounds__(256) void k_agg0(
    const uint* __restrict__ fbfu, const int* __restrict__ cnt,
    const int* __restrict__ bucket, const int* __restrict__ ovf_cnt,
    const int* __restrict__ ovf, uint* __restrict__ aggu) {
  int n = blockIdx.x * 4 + (threadIdx.x >> 6);
  int lane = threadIdx.x & 63;
  if (n >= N_NODES) return;
  int c = cnt[n];
  int kb = min(c, CAP);
  int id = (lane < kb) ? bucket[(size_t)n * CAP + lane] : 0;
  float2 acc = make_float2(0.f, 0.f);
  for (int j = 0; j < kb; ++j) {
    int s = __shfl(id, j, 64);
    float2 v = bfpair(fbfu[(size_t)s * 64 + lane]);
    acc.x += v.x;
    acc.y += v.y;
  }
  int oc = min(*ovf_cnt, OVF_CAP);
  for (int i = 0; i < oc; ++i) {
    if (ovf[2 * i + 1] == n) {
      float2 v = bfpair(fbfu[(size_t)ovf[2 * i] * 64 + lane]);
      acc.x += v.x;
      acc.y += v.y;
    }
  }
  float inv = 1.0f / (float)max(c, 1);
  aggu[(size_t)n * 64 + lane] = (uint)f2bf(acc.x * inv) |
                                ((uint)f2bf(acc.y * inv) << 16);
}

// ---------------- layer-0 MFMA GEMM: h = relu([feat|agg] @ Wp0 + b0) -------
// 128x128/block, 4 waves; wave = 64x64 = 4x4 C-frags; K=256 = 8 steps.
// aggb and h ALIAS (block reads own rows, overwrites post-barrier).
__global__ __launch_bounds__(256) void k_gemm0(
    const ushort* __restrict__ fbf, const ushort* aggb,
    const uint4* __restrict__ wp0g, const float* __restrict__ b0,
    ushort* h) {
  __shared__ uint4 wlds[4096];  // 64KB
  int tid = threadIdx.x;
#pragma unroll
  for (int i = 0; i < 16; ++i) wlds[i * 256 + tid] = wp0g[i * 256 + tid];
  __syncthreads();
  const short8* wl8 = reinterpret_cast<const short8*>(wlds);

  int lane = tid & 63, w = tid >> 6;
  int quad = lane >> 4, lm = lane & 15;
  int mw = blockIdx.x * 128 + (w >> 1) * 64;
  int tgb = (w & 1) * 4;

  f32x4 acc[4][4];
#pragma unroll
  for (int rt = 0; rt < 4; ++rt)
#pragma unroll
    for (int ct = 0; ct < 4; ++ct) acc[rt][ct] = (f32x4){0.f, 0.f, 0.f, 0.f};
  short8 az = {0, 0, 0, 0, 0, 0, 0, 0};

#pragma unroll
  for (int s = 0; s < 8; ++s) {
    const ushort* bsrc = (s < 4) ? fbf : aggb;
    int koff = (s & 3) * 32 + quad * 8;
    short8 a[4];
#pragma unroll
    for (int rt = 0; rt < 4; ++rt) {
      int row = mw + rt * 16 + lm;
      a[rt] = (row < N_NODES)
                  ? *reinterpret_cast<const short8*>(bsrc + (size_t)row * 128 + koff)
                  : az;
    }
#pragma unroll
    for (int ct = 0; ct < 4; ++ct) {
      short8 b = wl8[(s * 8 + tgb + ct) * 64 + lane];
#pragma unroll
      for (int rt = 0; rt < 4; ++rt)
        acc[rt][ct] =
            __builtin_amdgcn_mfma_f32_16x16x32_bf16(a[rt], b, acc[rt][ct], 0, 0, 0);
    }
  }

  __syncthreads();  // all waves done reading aggb before h overwrites
  float bv[4];
#pragma unroll
  for (int ct = 0; ct < 4; ++ct) bv[ct] = b0[(tgb + ct) * 16 + lm];
#pragma unroll
  for (int rt = 0; rt < 4; ++rt)
#pragma unroll
    for (int ct = 0; ct < 4; ++ct)
#pragma unroll
      for (int i = 0; i < 4; ++i) {
        int row = mw + rt * 16 + quad * 4 + i;
        if (row < N_NODES) {
          int col = (tgb + ct) * 16 + lm;
          h[(size_t)row * 128 + col] = f2bf(fmaxf(acc[rt][ct][i] + bv[ct], 0.f));
        }
      }
}

// ---------------- fused layer-1 MFMA GEMM: [hw | sout] = h @ Wp1 -----------
__global__ __launch_bounds__(256) void k_gemm1(
    const ushort* __restrict__ h, const uint4* __restrict__ wp1g,
    const float* __restrict__ b1, ushort* __restrict__ hw,
    float* __restrict__ out) {
  __shared__ uint4 wlds[2048];  // 32KB
  int tid = threadIdx.x;
#pragma unroll
  for (int i = 0; i < 8; ++i) wlds[i * 256 + tid] = wp1g[i * 256 + tid];
  __syncthreads();
  const short8* wl8 = reinterpret_cast<const short8*>(wlds);

  int lane = tid & 63, w = tid >> 6;
  int quad = lane >> 4, lm = lane & 15;
  int mw = blockIdx.x * 128 + (w >> 1) * 64;
  int tgb = (w & 1) * 4;

  f32x4 acc[4][4];
#pragma unroll
  for (int rt = 0; rt < 4; ++rt)
#pragma unroll
    for (int ct = 0; ct < 4; ++ct) acc[rt][ct] = (f32x4){0.f, 0.f, 0.f, 0.f};
  short8 az = {0, 0, 0, 0, 0, 0, 0, 0};

#pragma unroll
  for (int s = 0; s < 4; ++s) {
    int koff = s * 32 + quad * 8;
    short8 a[4];
#pragma unroll
    for (int rt = 0; rt < 4; ++rt) {
      int row = mw + rt * 16 + lm;
      a[rt] = (row < N_NODES)
                  ? *reinterpret_cast<const short8*>(h + (size_t)row * 128 + koff)
                  : az;
    }
#pragma unroll
    for (int ct = 0; ct < 4; ++ct) {
      short8 b = wl8[(s * 8 + tgb + ct) * 64 + lane];
#pragma unroll
      for (int rt = 0; rt < 4; ++rt)
        acc[rt][ct] =
            __builtin_amdgcn_mfma_f32_16x16x32_bf16(a[rt], b, acc[rt][ct], 0, 0, 0);
    }
  }

  if ((w & 1) == 0) {  // cols 0..63 -> hw = h@Wn1 (bf16)
#pragma unroll
    for (int rt = 0; rt < 4; ++rt)
#pragma unroll
      for (int ct = 0; ct < 4; ++ct)
#pragma unroll
        for (int i = 0; i < 4; ++i) {
          int row = mw + rt * 16 + quad * 4 + i;
          if (row < N_NODES)
            hw[(size_t)row * 64 + ct * 16 + lm] = f2bf(acc[rt][ct][i]);
        }
  } else {  // cols 64..127 -> out = h@Ws1 + b1 (f32)
    float bv[4];
#pragma unroll
    for (int ct = 0; ct < 4; ++ct) bv[ct] = b1[ct * 16 + lm];
#pragma unroll
    for (int rt = 0; rt < 4; ++rt)
#pragma unroll
      for (int ct = 0; ct < 4; ++ct)
#pragma unroll
        for (int i = 0; i < 4; ++i) {
          int row = mw + rt * 16 + quad * 4 + i;
          if (row < N_NODES)
            out[(size_t)row * 64 + ct * 16 + lm] = acc[rt][ct][i] + bv[ct];
        }
  }
}

// ---------------- layer-1 aggregation: out[n] += mean(hw[src]) -------------
__global__ __launch_bounds__(256) void k_agg1(
    const uint* __restrict__ hwu, const int* __restrict__ cnt,
    const int* __restrict__ bucket, const int* __restrict__ ovf_cnt,
    const int* __restrict__ ovf, float* __restrict__ out) {
  int n = blockIdx.x * 4 + (threadIdx.x >> 6);
  int lane = threadIdx.x & 63;
  if (n >= N_NODES) return;
  int half = lane >> 5;
  int li = lane & 31;
  int c = cnt[n];
  int kb = min(c, CAP);
  int id = (lane < kb) ? bucket[(size_t)n * CAP + lane] : 0;
  float2 acc = make_float2(0.f, 0.f);
  for (int j = 0; j < kb; j += 2) {
    int jj = j + half;
    int s = __shfl(id, jj, 64);
    if (jj < kb) {
      float2 v = bfpair(hwu[(size_t)s * 32 + li]);
      acc.x += v.x;
      acc.y += v.y;
    }
  }
  int oc = min(*ovf_cnt, OVF_CAP);
  for (int i = 0; i < oc; ++i) {
    if (half == 0 && ovf[2 * i + 1] == n) {
      float2 v = bfpair(hwu[(size_t)ovf[2 * i] * 32 + li]);
      acc.x += v.x;
      acc.y += v.y;
    }
  }
  acc.x += __shfl_xor(acc.x, 32, 64);
  acc.y += __shfl_xor(acc.y, 32, 64);
  if (half == 0) {
    float inv = 1.0f / (float)max(c, 1);
    float2 cur = *reinterpret_cast<float2*>(out + (size_t)n * OUTF + li * 2);
    cur.x += acc.x * inv;
    cur.y += acc.y * inv;
    *reinterpret_cast<float2*>(out + (size_t)n * OUTF + li * 2) = cur;
  }
}

extern "C" void kernel_launch(void* const* d_in, const int* in_sizes, int n_in,
                              void* d_out, int out_size, void* d_ws,
                              size_t ws_size, hipStream_t stream) {
  const float* feat = (const float*)d_in[0];
  const int* src = (const int*)d_in[1];
  const int* dst = (const int*)d_in[2];
  const float* Ws0 = (const float*)d_in[3];
  const float* Wn0 = (const float*)d_in[4];
  const float* b0 = (const float*)d_in[5];
  const float* Ws1 = (const float*)d_in[6];
  const float* Wn1 = (const float*)d_in[7];
  const float* b1 = (const float*)d_in[8];
  char* ws = (char*)d_ws;

  // Workspace (74.17 MB <= 77.2 MB proven):
  //   hbuf    @ 0          : 25,600,000  (phase1: binbuf 7.2MB; then agg0/h)
  //   cnt     @ 25,600,000 :    400,000
  //   ovf_cnt @ 26,000,000 :         64
  //   gcursor @ 26,000,064 :      1,600  (391 bin cursors)
  //   ovf     @ 26,001,664 :     65,536
  //   bucket  @ 26,067,200 : 22,400,000  (CAP=56)
  //   feat_bf @ 48,467,200 : 25,600,000  (bf16; hw reuses after gemm0)
  //   wp0     @ 74,067,200 :     65,536
  //   wp1     @ 74,132,736 :     32,768
  ushort* hbuf = (ushort*)(ws);
  uint* binbuf = (uint*)(ws);  // lives in hbuf region until k_scat done
  int* cnt = (int*)(ws + 25600000);
  int* ovf_cnt = (int*)(ws + 26000000);
  uint* gcursor = (uint*)(ws + 26000064);
  int* ovf = (int*)(ws + 26001664);
  int* bucket = (int*)(ws + 26067200);
  ushort* fbf = (ushort*)(ws + 48467200);
  ushort* hw = (ushort*)(ws + 48467200);  // reuses feat_bf post-gemm0
  ushort* wp0 = (ushort*)(ws + 74067200);
  ushort* wp1 = (ushort*)(ws + 74132736);
  float* out = (float*)d_out;

  hipMemsetAsync(ws + 25600000, 0, 467200, stream);  // cnt+ovf_cnt+gcursor+ovf
  k_prep<<<25192, 256, 0, stream>>>(feat, Ws0, Wn0, Ws1, Wn1, (uint*)fbf, wp0,
                                    wp1);
  k_bin<<<782, 512, 0, stream>>>(src, dst, gcursor, binbuf, ovf_cnt, ovf, cnt);
  k_scat<<<BINS, 256, 0, stream>>>(binbuf, gcursor, bucket, cnt, ovf_cnt, ovf);
  k_agg0<<<N_NODES / 4, 256, 0, stream>>>((const uint*)fbf, cnt, bucket,
                                          ovf_cnt, ovf, (uint*)hbuf);
  k_gemm0<<<GBLK, 256, 0, stream>>>(fbf, hbuf, (const uint4*)wp0, b0, hbuf);
  k_gemm1<<<GBLK, 256, 0, stream>>>(hbuf, (const uint4*)wp1, b1, hw, out);
  k_agg1<<<N_NODES / 4, 256, 0, stream>>>((const uint*)hw, cnt, bucket, ovf_cnt,
                                          ovf, out);
}

// Round 6
// 307.059 us; speedup vs baseline: 7.8046x; 1.2278x over previous
//
#include <hip/hip_runtime.h>

#define N_NODES 100000
#define N_EDGES 1600000
#define IN_F 128
#define HID 128
#define OUTF 64
#define CAP 56         // per-node bucket capacity (Poisson(16) tail ~ never)
#define OVF_CAP 8192
#define GBLK 782       // ceil(100000/128) gemm blocks
#define BINS 391       // ceil(100000/256): bin = dst>>8
#define BINCAP 4608    // Poisson(4096) + 8 sigma

typedef unsigned int uint;
typedef unsigned short ushort;
typedef __attribute__((ext_vector_type(8))) short short8;  // 8 bf16 (4 VGPRs)
typedef __attribute__((ext_vector_type(4))) float f32x4;   // 4 fp32 acc

__device__ __forceinline__ ushort f2bf(float f) {
  uint x = __float_as_uint(f);
  x += 0x7fffu + ((x >> 16) & 1u);  // round-to-nearest-even
  return (ushort)(x >> 16);
}
__device__ __forceinline__ float2 bfpair(uint u) {
  float2 r;
  r.x = __uint_as_float(u << 16);
  r.y = __uint_as_float(u & 0xffff0000u);
  return r;
}

// ---------------- fused prep: feat f32->bf16 + weight B-frag packing -------
// B-frag layout (16x16x32 bf16): lane = 16q+c holds B[k=8q+j][n=16t+c].
// Wp0 = [Ws0; Wn0] (K=256, N=128); Wp1 = [Wn1 | Ws1] (K=128, N=128).
__global__ __launch_bounds__(256) void k_prep(
    const float* __restrict__ feat, const float* __restrict__ Ws0,
    const float* __restrict__ Wn0, const float* __restrict__ Ws1,
    const float* __restrict__ Wn1, uint* __restrict__ fbfu,
    ushort* __restrict__ wp0, ushort* __restrict__ wp1) {
  int b = blockIdx.x;
  int tid = threadIdx.x;
  if (b < 25000) {  // feat conversion: N*64 uint outputs
    int i = b * 256 + tid;
    float2 v = reinterpret_cast<const float2*>(feat)[i];
    fbfu[i] = (uint)f2bf(v.x) | ((uint)f2bf(v.y) << 16);
    return;
  }
  int idx = (b - 25000) * 256 + tid;  // 49152 = 32768 + 16384
  if (idx < 32768) {
    int k = idx >> 7, n = idx & 127;
    float v = (k < 128) ? Ws0[k * 128 + n] : Wn0[(k - 128) * 128 + n];
    int s = k >> 5, q = (k >> 3) & 3, j = k & 7;
    int t = n >> 4, c = n & 15;
    wp0[(((s * 8 + t) * 64) + (q * 16 + c)) * 8 + j] = f2bf(v);
  } else {
    int i2 = idx - 32768;
    int k = i2 >> 7, n = i2 & 127;
    float v = (n < 64) ? Wn1[k * 64 + n] : Ws1[k * 64 + (n - 64)];
    int s = k >> 5, q = (k >> 3) & 3, j = k & 7;
    int t = n >> 4, c = n & 15;
    wp1[(((s * 8 + t) * 64) + (q * 16 + c)) * 8 + j] = f2bf(v);
  }
}

// ---------------- bin phase 1: dense per-bin edge segments -----------------
__global__ __launch_bounds__(512) void k_bin(
    const int* __restrict__ src, const int* __restrict__ dst,
    uint* __restrict__ gcursor, uint* __restrict__ binbuf,
    int* __restrict__ ovf_cnt, int* __restrict__ ovf, int* __restrict__ cnt) {
  __shared__ uint hist[BINS];
  __shared__ uint base[BINS];
  int tid = threadIdx.x;
  for (int i = tid; i < BINS; i += 512) hist[i] = 0;
  __syncthreads();

  int e0 = blockIdx.x * 2048;
  uint val[4], bin[4], rank[4];
  int valid[4];
#pragma unroll
  for (int it = 0; it < 4; ++it) {
    int e = e0 + it * 512 + tid;
    valid[it] = (e < N_EDGES);
    if (valid[it]) {
      uint s = (uint)src[e];
      uint d = (uint)dst[e];
      bin[it] = d >> 8;
      rank[it] = atomicAdd(&hist[bin[it]], 1u);
      val[it] = s | ((d & 255u) << 17);
    }
  }
  __syncthreads();
  for (int i = tid; i < BINS; i += 512)
    base[i] = hist[i] ? atomicAdd(&gcursor[i], hist[i]) : 0u;
  __syncthreads();

#pragma unroll
  for (int it = 0; it < 4; ++it) {
    if (!valid[it]) continue;
    uint p = base[bin[it]] + rank[it];
    if (p < BINCAP) {
      binbuf[(size_t)bin[it] * BINCAP + p] = val[it];
    } else {  // astronomically rare: binbuf overflow -> ovf list + cnt
      int s = (int)(val[it] & 0x1FFFFu);
      int d = (int)(bin[it] * 256 + (val[it] >> 17));
      int o = atomicAdd(ovf_cnt, 1);
      if (o < OVF_CAP) {
        ovf[2 * o] = s;
        ovf[2 * o + 1] = d;
      }
      atomicAdd(&cnt[d], 1);
    }
  }
}

// ---------------- bin phase 2: exclusive per-bin scatter -------------------
__global__ __launch_bounds__(256) void k_scat(
    const uint* __restrict__ binbuf, const uint* __restrict__ gcursor,
    int* __restrict__ bucket, int* __restrict__ cnt, int* __restrict__ ovf_cnt,
    int* __restrict__ ovf) {
  __shared__ uint lcnt[256];
  int b = blockIdx.x;
  int tid = threadIdx.x;
  lcnt[tid] = 0;
  __syncthreads();
  int ne = min((int)gcursor[b], BINCAP);
  for (int i = tid; i < ne; i += 256) {
    uint v = binbuf[(size_t)b * BINCAP + i];
    int s = (int)(v & 0x1FFFFu);
    uint dl = v >> 17;
    uint pos = atomicAdd(&lcnt[dl], 1u);
    int d = b * 256 + (int)dl;
    if (pos < CAP) {
      bucket[(size_t)d * CAP + pos] = s;
    } else {
      int o = atomicAdd(ovf_cnt, 1);
      if (o < OVF_CAP) {
        ovf[2 * o] = s;
        ovf[2 * o + 1] = d;
      }
    }
  }
  __syncthreads();
  int d = b * 256 + tid;
  if (d < N_NODES && lcnt[tid]) atomicAdd(&cnt[d], (int)lcnt[tid]);
}

// ---------------- layer-0 aggregation: agg0[n] = mean(feat_bf[src]) --------
// Half-wave per 256B row (32 lanes x uint2), unroll x4 -> 8 edges per wave
// iteration, 4 independent loads in flight per lane (MLP, latency hiding).
__global__ __launch_bounds__(256) void k_agg0(
    const uint2* __restrict__ fbf2, const int* __restrict__ cnt,
    const int* __restrict__ bucket, const int* __restrict__ ovf_cnt,
    const int* __restrict__ ovf, uint2* __restrict__ agg2) {
  int n = blockIdx.x * 4 + (threadIdx.x >> 6);
  int lane = threadIdx.x & 63;
  if (n >= N_NODES) return;
  int half = lane >> 5;  // 0/1: which edge of the pair
  int li = lane & 31;    // position within the 256B row
  int c = cnt[n];
  int kb = min(c, CAP);
  int id = (lane < kb) ? bucket[(size_t)n * CAP + lane] : 0;
  float acc0 = 0.f, acc1 = 0.f, acc2 = 0.f, acc3 = 0.f;
  int j = 0;
  for (; j + 8 <= kb; j += 8) {
    int s0 = __shfl(id, j + half, 64);
    int s1 = __shfl(id, j + 2 + half, 64);
    int s2 = __shfl(id, j + 4 + half, 64);
    int s3 = __shfl(id, j + 6 + half, 64);
    uint2 u0 = fbf2[(size_t)s0 * 32 + li];
    uint2 u1 = fbf2[(size_t)s1 * 32 + li];
    uint2 u2 = fbf2[(size_t)s2 * 32 + li];
    uint2 u3 = fbf2[(size_t)s3 * 32 + li];
    float2 a, b;
    a = bfpair(u0.x); b = bfpair(u0.y);
    acc0 += a.x; acc1 += a.y; acc2 += b.x; acc3 += b.y;
    a = bfpair(u1.x); b = bfpair(u1.y);
    acc0 += a.x; acc1 += a.y; acc2 += b.x; acc3 += b.y;
    a = bfpair(u2.x); b = bfpair(u2.y);
    acc0 += a.x; acc1 += a.y; acc2 += b.x; acc3 += b.y;
    a = bfpair(u3.x); b = bfpair(u3.y);
    acc0 += a.x; acc1 += a.y; acc2 += b.x; acc3 += b.y;
  }
  for (; j < kb; j += 2) {
    int e = j + half;
    int s = __shfl(id, min(e, kb - 1), 64);
    if (e < kb) {
      uint2 u = fbf2[(size_t)s * 32 + li];
      float2 a = bfpair(u.x), b = bfpair(u.y);
      acc0 += a.x; acc1 += a.y; acc2 += b.x; acc3 += b.y;
    }
  }
  // cold overflow path: entry i handled by half (i&1)
  int oc = min(*ovf_cnt, OVF_CAP);
  for (int i = 0; i < oc; ++i) {
    if ((i & 1) == half && ovf[2 * i + 1] == n) {
      uint2 u = fbf2[(size_t)ovf[2 * i] * 32 + li];
      float2 a = bfpair(u.x), b = bfpair(u.y);
      acc0 += a.x; acc1 += a.y; acc2 += b.x; acc3 += b.y;
    }
  }
  acc0 += __shfl_xor(acc0, 32, 64);
  acc1 += __shfl_xor(acc1, 32, 64);
  acc2 += __shfl_xor(acc2, 32, 64);
  acc3 += __shfl_xor(acc3, 32, 64);
  if (half == 0) {
    float inv = 1.0f / (float)max(c, 1);
    uint2 o;
    o.x = (uint)f2bf(acc0 * inv) | ((uint)f2bf(acc1 * inv) << 16);
    o.y = (uint)f2bf(acc2 * inv) | ((uint)f2bf(acc3 * inv) << 16);
    agg2[(size_t)n * 32 + li] = o;
  }
}

// ---------------- layer-0 MFMA GEMM: h = relu([feat|agg] @ Wp0 + b0) -------
// 128x128/block, 4 waves; wave = 64x64 = 4x4 C-frags; K=256 = 8 steps.
// aggb and h ALIAS (block reads own rows, overwrites post-barrier).
__global__ __launch_bounds__(256) void k_gemm0(
    const ushort* __restrict__ fbf, const ushort* aggb,
    const uint4* __restrict__ wp0g, const float* __restrict__ b0,
    ushort* h) {
  __shared__ uint4 wlds[4096];  // 64KB
  int tid = threadIdx.x;
#pragma unroll
  for (int i = 0; i < 16; ++i) wlds[i * 256 + tid] = wp0g[i * 256 + tid];
  __syncthreads();
  const short8* wl8 = reinterpret_cast<const short8*>(wlds);

  int lane = tid & 63, w = tid >> 6;
  int quad = lane >> 4, lm = lane & 15;
  int mw = blockIdx.x * 128 + (w >> 1) * 64;
  int tgb = (w & 1) * 4;

  f32x4 acc[4][4];
#pragma unroll
  for (int rt = 0; rt < 4; ++rt)
#pragma unroll
    for (int ct = 0; ct < 4; ++ct) acc[rt][ct] = (f32x4){0.f, 0.f, 0.f, 0.f};
  short8 az = {0, 0, 0, 0, 0, 0, 0, 0};

#pragma unroll
  for (int s = 0; s < 8; ++s) {
    const ushort* bsrc = (s < 4) ? fbf : aggb;
    int koff = (s & 3) * 32 + quad * 8;
    short8 a[4];
#pragma unroll
    for (int rt = 0; rt < 4; ++rt) {
      int row = mw + rt * 16 + lm;
      a[rt] = (row < N_NODES)
                  ? *reinterpret_cast<const short8*>(bsrc + (size_t)row * 128 + koff)
                  : az;
    }
#pragma unroll
    for (int ct = 0; ct < 4; ++ct) {
      short8 b = wl8[(s * 8 + tgb + ct) * 64 + lane];
#pragma unroll
      for (int rt = 0; rt < 4; ++rt)
        acc[rt][ct] =
            __builtin_amdgcn_mfma_f32_16x16x32_bf16(a[rt], b, acc[rt][ct], 0, 0, 0);
    }
  }

  __syncthreads();  // all waves done reading aggb before h overwrites
  float bv[4];
#pragma unroll
  for (int ct = 0; ct < 4; ++ct) bv[ct] = b0[(tgb + ct) * 16 + lm];
#pragma unroll
  for (int rt = 0; rt < 4; ++rt)
#pragma unroll
    for (int ct = 0; ct < 4; ++ct)
#pragma unroll
      for (int i = 0; i < 4; ++i) {
        int row = mw + rt * 16 + quad * 4 + i;
        if (row < N_NODES) {
          int col = (tgb + ct) * 16 + lm;
          h[(size_t)row * 128 + col] = f2bf(fmaxf(acc[rt][ct][i] + bv[ct], 0.f));
        }
      }
}

// ---------------- fused layer-1 MFMA GEMM: [hw | sout] = h @ Wp1 -----------
__global__ __launch_bounds__(256) void k_gemm1(
    const ushort* __restrict__ h, const uint4* __restrict__ wp1g,
    const float* __restrict__ b1, ushort* __restrict__ hw,
    float* __restrict__ out) {
  __shared__ uint4 wlds[2048];  // 32KB
  int tid = threadIdx.x;
#pragma unroll
  for (int i = 0; i < 8; ++i) wlds[i * 256 + tid] = wp1g[i * 256 + tid];
  __syncthreads();
  const short8* wl8 = reinterpret_cast<const short8*>(wlds);

  int lane = tid & 63, w = tid >> 6;
  int quad = lane >> 4, lm = lane & 15;
  int mw = blockIdx.x * 128 + (w >> 1) * 64;
  int tgb = (w & 1) * 4;

  f32x4 acc[4][4];
#pragma unroll
  for (int rt = 0; rt < 4; ++rt)
#pragma unroll
    for (int ct = 0; ct < 4; ++ct) acc[rt][ct] = (f32x4){0.f, 0.f, 0.f, 0.f};
  short8 az = {0, 0, 0, 0, 0, 0, 0, 0};

#pragma unroll
  for (int s = 0; s < 4; ++s) {
    int koff = s * 32 + quad * 8;
    short8 a[4];
#pragma unroll
    for (int rt = 0; rt < 4; ++rt) {
      int row = mw + rt * 16 + lm;
      a[rt] = (row < N_NODES)
                  ? *reinterpret_cast<const short8*>(h + (size_t)row * 128 + koff)
                  : az;
    }
#pragma unroll
    for (int ct = 0; ct < 4; ++ct) {
      short8 b = wl8[(s * 8 + tgb + ct) * 64 + lane];
#pragma unroll
      for (int rt = 0; rt < 4; ++rt)
        acc[rt][ct] =
            __builtin_amdgcn_mfma_f32_16x16x32_bf16(a[rt], b, acc[rt][ct], 0, 0, 0);
    }
  }

  if ((w & 1) == 0) {  // cols 0..63 -> hw = h@Wn1 (bf16)
#pragma unroll
    for (int rt = 0; rt < 4; ++rt)
#pragma unroll
      for (int ct = 0; ct < 4; ++ct)
#pragma unroll
        for (int i = 0; i < 4; ++i) {
          int row = mw + rt * 16 + quad * 4 + i;
          if (row < N_NODES)
            hw[(size_t)row * 64 + ct * 16 + lm] = f2bf(acc[rt][ct][i]);
        }
  } else {  // cols 64..127 -> out = h@Ws1 + b1 (f32)
    float bv[4];
#pragma unroll
    for (int ct = 0; ct < 4; ++ct) bv[ct] = b1[ct * 16 + lm];
#pragma unroll
    for (int rt = 0; rt < 4; ++rt)
#pragma unroll
      for (int ct = 0; ct < 4; ++ct)
#pragma unroll
        for (int i = 0; i < 4; ++i) {
          int row = mw + rt * 16 + quad * 4 + i;
          if (row < N_NODES)
            out[(size_t)row * 64 + ct * 16 + lm] = acc[rt][ct][i] + bv[ct];
        }
  }
}

// ---------------- layer-1 aggregation: out[n] += mean(hw[src]) -------------
// Quarter-wave per 128B row (16 lanes x uint2), unroll x2 -> 8 edges per
// wave iteration, 2 loads in flight per lane.
__global__ __launch_bounds__(256) void k_agg1(
    const uint2* __restrict__ hw2, const int* __restrict__ cnt,
    const int* __restrict__ bucket, const int* __restrict__ ovf_cnt,
    const int* __restrict__ ovf, float* __restrict__ out) {
  int n = blockIdx.x * 4 + (threadIdx.x >> 6);
  int lane = threadIdx.x & 63;
  if (n >= N_NODES) return;
  int q = lane >> 4;   // 0..3: which edge of the quad
  int li = lane & 15;  // position within the 128B row
  int c = cnt[n];
  int kb = min(c, CAP);
  int id = (lane < kb) ? bucket[(size_t)n * CAP + lane] : 0;
  float acc0 = 0.f, acc1 = 0.f, acc2 = 0.f, acc3 = 0.f;
  int j = 0;
  for (; j + 8 <= kb; j += 8) {
    int s0 = __shfl(id, j + q, 64);
    int s1 = __shfl(id, j + 4 + q, 64);
    uint2 u0 = hw2[(size_t)s0 * 16 + li];
    uint2 u1 = hw2[(size_t)s1 * 16 + li];
    float2 a, b;
    a = bfpair(u0.x); b = bfpair(u0.y);
    acc0 += a.x; acc1 += a.y; acc2 += b.x; acc3 += b.y;
    a = bfpair(u1.x); b = bfpair(u1.y);
    acc0 += a.x; acc1 += a.y; acc2 += b.x; acc3 += b.y;
  }
  for (; j < kb; j += 4) {
    int e = j + q;
    int s = __shfl(id, min(e, kb - 1), 64);
    if (e < kb) {
      uint2 u = hw2[(size_t)s * 16 + li];
      float2 a = bfpair(u.x), b = bfpair(u.y);
      acc0 += a.x; acc1 += a.y; acc2 += b.x; acc3 += b.y;
    }
  }
  // cold overflow path: entry i handled by quarter (i&3)
  int oc = min(*ovf_cnt, OVF_CAP);
  for (int i = 0; i < oc; ++i) {
    if ((i & 3) == q && ovf[2 * i + 1] == n) {
      uint2 u = hw2[(size_t)ovf[2 * i] * 16 + li];
      float2 a = bfpair(u.x), b = bfpair(u.y);
      acc0 += a.x; acc1 += a.y; acc2 += b.x; acc3 += b.y;
    }
  }
  acc0 += __shfl_xor(acc0, 16, 64);
  acc1 += __shfl_xor(acc1, 16, 64);
  acc2 += __shfl_xor(acc2, 16, 64);
  acc3 += __shfl_xor(acc3, 16, 64);
  acc0 += __shfl_xor(acc0, 32, 64);
  acc1 += __shfl_xor(acc1, 32, 64);
  acc2 += __shfl_xor(acc2, 32, 64);
  acc3 += __shfl_xor(acc3, 32, 64);
  if (q == 0) {
    float inv = 1.0f / (float)max(c, 1);
    float4 cur = *reinterpret_cast<float4*>(out + (size_t)n * OUTF + li * 4);
    cur.x += acc0 * inv;
    cur.y += acc1 * inv;
    cur.z += acc2 * inv;
    cur.w += acc3 * inv;
    *reinterpret_cast<float4*>(out + (size_t)n * OUTF + li * 4) = cur;
  }
}

extern "C" void kernel_launch(void* const* d_in, const int* in_sizes, int n_in,
                              void* d_out, int out_size, void* d_ws,
                              size_t ws_size, hipStream_t stream) {
  const float* feat = (const float*)d_in[0];
  const int* src = (const int*)d_in[1];
  const int* dst = (const int*)d_in[2];
  const float* Ws0 = (const float*)d_in[3];
  const float* Wn0 = (const float*)d_in[4];
  const float* b0 = (const float*)d_in[5];
  const float* Ws1 = (const float*)d_in[6];
  const float* Wn1 = (const float*)d_in[7];
  const float* b1 = (const float*)d_in[8];
  char* ws = (char*)d_ws;

  // Workspace (74.17 MB <= 77.2 MB proven):
  //   hbuf    @ 0          : 25,600,000  (phase1: binbuf 7.2MB; then agg0/h)
  //   cnt     @ 25,600,000 :    400,000
  //   ovf_cnt @ 26,000,000 :         64
  //   gcursor @ 26,000,064 :      1,600  (391 bin cursors)
  //   ovf     @ 26,001,664 :     65,536
  //   bucket  @ 26,067,200 : 22,400,000  (CAP=56)
  //   feat_bf @ 48,467,200 : 25,600,000  (bf16; hw reuses after gemm0)
  //   wp0     @ 74,067,200 :     65,536
  //   wp1     @ 74,132,736 :     32,768
  ushort* hbuf = (ushort*)(ws);
  uint* binbuf = (uint*)(ws);  // lives in hbuf region until k_scat done
  int* cnt = (int*)(ws + 25600000);
  int* ovf_cnt = (int*)(ws + 26000000);
  uint* gcursor = (uint*)(ws + 26000064);
  int* ovf = (int*)(ws + 26001664);
  int* bucket = (int*)(ws + 26067200);
  ushort* fbf = (ushort*)(ws + 48467200);
  ushort* hw = (ushort*)(ws + 48467200);  // reuses feat_bf post-gemm0
  ushort* wp0 = (ushort*)(ws + 74067200);
  ushort* wp1 = (ushort*)(ws + 74132736);
  float* out = (float*)d_out;

  hipMemsetAsync(ws + 25600000, 0, 467200, stream);  // cnt+ovf_cnt+gcursor+ovf
  k_prep<<<25192, 256, 0, stream>>>(feat, Ws0, Wn0, Ws1, Wn1, (uint*)fbf, wp0,
                                    wp1);
  k_bin<<<782, 512, 0, stream>>>(src, dst, gcursor, binbuf, ovf_cnt, ovf, cnt);
  k_scat<<<BINS, 256, 0, stream>>>(binbuf, gcursor, bucket, cnt, ovf_cnt, ovf);
  k_agg0<<<N_NODES / 4, 256, 0, stream>>>((const uint2*)fbf, cnt, bucket,
                                          ovf_cnt, ovf, (uint2*)hbuf);
  k_gemm0<<<GBLK, 256, 0, stream>>>(fbf, hbuf, (const uint4*)wp0, b0, hbuf);
  k_gemm1<<<GBLK, 256, 0, stream>>>(hbuf, (const uint4*)wp1, b1, hw, out);
  k_agg1<<<N_NODES / 4, 256, 0, stream>>>((const uint2*)hw, cnt, bucket,
                                          ovf_cnt, ovf, out);
}

// Round 7
// 300.107 us; speedup vs baseline: 7.9854x; 1.0232x over previous
//
#include <hip/hip_runtime.h>

#define N_NODES 100000
#define N_EDGES 1600000
#define IN_F 128
#define HID 128
#define OUTF 64
#define CAP 56         // per-node bucket capacity (Poisson(16) tail ~ never)
#define OVF_CAP 8192
#define GBLK 782       // ceil(100000/128) gemm blocks
#define BINS 391       // ceil(100000/256): bin = dst>>8
#define BINCAP 4608    // Poisson(4096) + 8 sigma

typedef unsigned int uint;
typedef unsigned short ushort;
typedef __attribute__((ext_vector_type(8))) short short8;  // 8 bf16 (4 VGPRs)
typedef __attribute__((ext_vector_type(4))) float f32x4;   // 4 fp32 acc

__device__ __forceinline__ ushort f2bf(float f) {
  uint x = __float_as_uint(f);
  x += 0x7fffu + ((x >> 16) & 1u);  // round-to-nearest-even
  return (ushort)(x >> 16);
}
__device__ __forceinline__ float2 bfpair(uint u) {
  float2 r;
  r.x = __uint_as_float(u << 16);
  r.y = __uint_as_float(u & 0xffff0000u);
  return r;
}

// unpack uint4 (8 bf16) and add into acc[0..7]
#define ACC8(u)                                   \
  {                                               \
    float2 _a;                                    \
    _a = bfpair((u).x); acc[0] += _a.x; acc[1] += _a.y; \
    _a = bfpair((u).y); acc[2] += _a.x; acc[3] += _a.y; \
    _a = bfpair((u).z); acc[4] += _a.x; acc[5] += _a.y; \
    _a = bfpair((u).w); acc[6] += _a.x; acc[7] += _a.y; \
  }

// ---------------- fused prep: feat f32->bf16 + weight B-frag packing -------
// B-frag layout (16x16x32 bf16): lane = 16q+c holds B[k=8q+j][n=16t+c].
// Wp0 = [Ws0; Wn0] (K=256, N=128); Wp1 = [Wn1 | Ws1] (K=128, N=128).
__global__ __launch_bounds__(256) void k_prep(
    const float* __restrict__ feat, const float* __restrict__ Ws0,
    const float* __restrict__ Wn0, const float* __restrict__ Ws1,
    const float* __restrict__ Wn1, uint* __restrict__ fbfu,
    ushort* __restrict__ wp0, ushort* __restrict__ wp1) {
  int b = blockIdx.x;
  int tid = threadIdx.x;
  if (b < 25000) {  // feat conversion: N*64 uint outputs
    int i = b * 256 + tid;
    float2 v = reinterpret_cast<const float2*>(feat)[i];
    fbfu[i] = (uint)f2bf(v.x) | ((uint)f2bf(v.y) << 16);
    return;
  }
  int idx = (b - 25000) * 256 + tid;  // 49152 = 32768 + 16384
  if (idx < 32768) {
    int k = idx >> 7, n = idx & 127;
    float v = (k < 128) ? Ws0[k * 128 + n] : Wn0[(k - 128) * 128 + n];
    int s = k >> 5, q = (k >> 3) & 3, j = k & 7;
    int t = n >> 4, c = n & 15;
    wp0[(((s * 8 + t) * 64) + (q * 16 + c)) * 8 + j] = f2bf(v);
  } else {
    int i2 = idx - 32768;
    int k = i2 >> 7, n = i2 & 127;
    float v = (n < 64) ? Wn1[k * 64 + n] : Ws1[k * 64 + (n - 64)];
    int s = k >> 5, q = (k >> 3) & 3, j = k & 7;
    int t = n >> 4, c = n & 15;
    wp1[(((s * 8 + t) * 64) + (q * 16 + c)) * 8 + j] = f2bf(v);
  }
}

// ---------------- bin phase 1: dense per-bin edge segments -----------------
__global__ __launch_bounds__(512) void k_bin(
    const int* __restrict__ src, const int* __restrict__ dst,
    uint* __restrict__ gcursor, uint* __restrict__ binbuf,
    int* __restrict__ ovf_cnt, int* __restrict__ ovf, int* __restrict__ cnt) {
  __shared__ uint hist[BINS];
  __shared__ uint base[BINS];
  int tid = threadIdx.x;
  for (int i = tid; i < BINS; i += 512) hist[i] = 0;
  __syncthreads();

  int e0 = blockIdx.x * 2048;
  uint val[4], bin[4], rank[4];
  int valid[4];
#pragma unroll
  for (int it = 0; it < 4; ++it) {
    int e = e0 + it * 512 + tid;
    valid[it] = (e < N_EDGES);
    if (valid[it]) {
      uint s = (uint)src[e];
      uint d = (uint)dst[e];
      bin[it] = d >> 8;
      rank[it] = atomicAdd(&hist[bin[it]], 1u);
      val[it] = s | ((d & 255u) << 17);
    }
  }
  __syncthreads();
  for (int i = tid; i < BINS; i += 512)
    base[i] = hist[i] ? atomicAdd(&gcursor[i], hist[i]) : 0u;
  __syncthreads();

#pragma unroll
  for (int it = 0; it < 4; ++it) {
    if (!valid[it]) continue;
    uint p = base[bin[it]] + rank[it];
    if (p < BINCAP) {
      binbuf[(size_t)bin[it] * BINCAP + p] = val[it];
    } else {  // astronomically rare: binbuf overflow -> ovf list + cnt
      int s = (int)(val[it] & 0x1FFFFu);
      int d = (int)(bin[it] * 256 + (val[it] >> 17));
      int o = atomicAdd(ovf_cnt, 1);
      if (o < OVF_CAP) {
        ovf[2 * o] = s;
        ovf[2 * o + 1] = d;
      }
      atomicAdd(&cnt[d], 1);
    }
  }
}

// ---------------- bin phase 2: exclusive per-bin scatter -------------------
__global__ __launch_bounds__(256) void k_scat(
    const uint* __restrict__ binbuf, const uint* __restrict__ gcursor,
    int* __restrict__ bucket, int* __restrict__ cnt, int* __restrict__ ovf_cnt,
    int* __restrict__ ovf) {
  __shared__ uint lcnt[256];
  int b = blockIdx.x;
  int tid = threadIdx.x;
  lcnt[tid] = 0;
  __syncthreads();
  int ne = min((int)gcursor[b], BINCAP);
  for (int i = tid; i < ne; i += 256) {
    uint v = binbuf[(size_t)b * BINCAP + i];
    int s = (int)(v & 0x1FFFFu);
    uint dl = v >> 17;
    uint pos = atomicAdd(&lcnt[dl], 1u);
    int d = b * 256 + (int)dl;
    if (pos < CAP) {
      bucket[(size_t)d * CAP + pos] = s;
    } else {
      int o = atomicAdd(ovf_cnt, 1);
      if (o < OVF_CAP) {
        ovf[2 * o] = s;
        ovf[2 * o + 1] = d;
      }
    }
  }
  __syncthreads();
  int d = b * 256 + tid;
  if (d < N_NODES && lcnt[tid]) atomicAdd(&cnt[d], (int)lcnt[tid]);
}

// ---------------- layer-0 aggregation: agg0[n] = mean(feat_bf[src]) --------
// Quarter-wave per 256B row (16 lanes x uint4), unroll x4 -> 16 edges per
// wave iteration, 4 x 16B loads in flight per lane (64B MLP per lane).
__global__ __launch_bounds__(256) void k_agg0(
    const uint4* __restrict__ fbf4, const int* __restrict__ cnt,
    const int* __restrict__ bucket, const int* __restrict__ ovf_cnt,
    const int* __restrict__ ovf, uint4* __restrict__ agg4) {
  int n = blockIdx.x * 4 + (threadIdx.x >> 6);
  int lane = threadIdx.x & 63;
  if (n >= N_NODES) return;
  int q = lane >> 4;   // 0..3: edge slot
  int li = lane & 15;  // 16B chunk within the 256B row
  int c = cnt[n];
  int kb = min(c, CAP);
  int id = (lane < kb) ? bucket[(size_t)n * CAP + lane] : 0;
  float acc[8] = {0.f, 0.f, 0.f, 0.f, 0.f, 0.f, 0.f, 0.f};
  int j = 0;
  for (; j + 16 <= kb; j += 16) {
    int s0 = __shfl(id, j + q, 64);
    int s1 = __shfl(id, j + 4 + q, 64);
    int s2 = __shfl(id, j + 8 + q, 64);
    int s3 = __shfl(id, j + 12 + q, 64);
    uint4 u0 = fbf4[(size_t)s0 * 16 + li];
    uint4 u1 = fbf4[(size_t)s1 * 16 + li];
    uint4 u2 = fbf4[(size_t)s2 * 16 + li];
    uint4 u3 = fbf4[(size_t)s3 * 16 + li];
    ACC8(u0);
    ACC8(u1);
    ACC8(u2);
    ACC8(u3);
  }
  for (; j < kb; j += 4) {
    int e = j + q;
    int s = __shfl(id, min(e, kb - 1), 64);
    if (e < kb) {
      uint4 u = fbf4[(size_t)s * 16 + li];
      ACC8(u);
    }
  }
  // cold overflow path: entry i handled by slot (i&3)
  int oc = min(*ovf_cnt, OVF_CAP);
  for (int i = 0; i < oc; ++i) {
    if ((i & 3) == q && ovf[2 * i + 1] == n) {
      uint4 u = fbf4[(size_t)ovf[2 * i] * 16 + li];
      ACC8(u);
    }
  }
#pragma unroll
  for (int k = 0; k < 8; ++k) {
    acc[k] += __shfl_xor(acc[k], 16, 64);
    acc[k] += __shfl_xor(acc[k], 32, 64);
  }
  if (q == 0) {
    float inv = 1.0f / (float)max(c, 1);
    uint4 o;
    o.x = (uint)f2bf(acc[0] * inv) | ((uint)f2bf(acc[1] * inv) << 16);
    o.y = (uint)f2bf(acc[2] * inv) | ((uint)f2bf(acc[3] * inv) << 16);
    o.z = (uint)f2bf(acc[4] * inv) | ((uint)f2bf(acc[5] * inv) << 16);
    o.w = (uint)f2bf(acc[6] * inv) | ((uint)f2bf(acc[7] * inv) << 16);
    agg4[(size_t)n * 16 + li] = o;
  }
}

// ---------------- layer-0 MFMA GEMM: h = relu([feat|agg] @ Wp0 + b0) -------
// 128x128/block, 4 waves; wave = 64x64 = 4x4 C-frags; K=256 = 8 steps.
// aggb and h ALIAS (block reads own rows, overwrites post-barrier).
__global__ __launch_bounds__(256) void k_gemm0(
    const ushort* __restrict__ fbf, const ushort* aggb,
    const uint4* __restrict__ wp0g, const float* __restrict__ b0,
    ushort* h) {
  __shared__ uint4 wlds[4096];  // 64KB
  int tid = threadIdx.x;
#pragma unroll
  for (int i = 0; i < 16; ++i) wlds[i * 256 + tid] = wp0g[i * 256 + tid];
  __syncthreads();
  const short8* wl8 = reinterpret_cast<const short8*>(wlds);

  int lane = tid & 63, w = tid >> 6;
  int quad = lane >> 4, lm = lane & 15;
  int mw = blockIdx.x * 128 + (w >> 1) * 64;
  int tgb = (w & 1) * 4;

  f32x4 acc[4][4];
#pragma unroll
  for (int rt = 0; rt < 4; ++rt)
#pragma unroll
    for (int ct = 0; ct < 4; ++ct) acc[rt][ct] = (f32x4){0.f, 0.f, 0.f, 0.f};
  short8 az = {0, 0, 0, 0, 0, 0, 0, 0};

#pragma unroll
  for (int s = 0; s < 8; ++s) {
    const ushort* bsrc = (s < 4) ? fbf : aggb;
    int koff = (s & 3) * 32 + quad * 8;
    short8 a[4];
#pragma unroll
    for (int rt = 0; rt < 4; ++rt) {
      int row = mw + rt * 16 + lm;
      a[rt] = (row < N_NODES)
                  ? *reinterpret_cast<const short8*>(bsrc + (size_t)row * 128 + koff)
                  : az;
    }
#pragma unroll
    for (int ct = 0; ct < 4; ++ct) {
      short8 b = wl8[(s * 8 + tgb + ct) * 64 + lane];
#pragma unroll
      for (int rt = 0; rt < 4; ++rt)
        acc[rt][ct] =
            __builtin_amdgcn_mfma_f32_16x16x32_bf16(a[rt], b, acc[rt][ct], 0, 0, 0);
    }
  }

  __syncthreads();  // all waves done reading aggb before h overwrites
  float bv[4];
#pragma unroll
  for (int ct = 0; ct < 4; ++ct) bv[ct] = b0[(tgb + ct) * 16 + lm];
#pragma unroll
  for (int rt = 0; rt < 4; ++rt)
#pragma unroll
    for (int ct = 0; ct < 4; ++ct)
#pragma unroll
      for (int i = 0; i < 4; ++i) {
        int row = mw + rt * 16 + quad * 4 + i;
        if (row < N_NODES) {
          int col = (tgb + ct) * 16 + lm;
          h[(size_t)row * 128 + col] = f2bf(fmaxf(acc[rt][ct][i] + bv[ct], 0.f));
        }
      }
}

// ---------------- fused layer-1 MFMA GEMM: [hw | sout] = h @ Wp1 -----------
__global__ __launch_bounds__(256) void k_gemm1(
    const ushort* __restrict__ h, const uint4* __restrict__ wp1g,
    const float* __restrict__ b1, ushort* __restrict__ hw,
    float* __restrict__ out) {
  __shared__ uint4 wlds[2048];  // 32KB
  int tid = threadIdx.x;
#pragma unroll
  for (int i = 0; i < 8; ++i) wlds[i * 256 + tid] = wp1g[i * 256 + tid];
  __syncthreads();
  const short8* wl8 = reinterpret_cast<const short8*>(wlds);

  int lane = tid & 63, w = tid >> 6;
  int quad = lane >> 4, lm = lane & 15;
  int mw = blockIdx.x * 128 + (w >> 1) * 64;
  int tgb = (w & 1) * 4;

  f32x4 acc[4][4];
#pragma unroll
  for (int rt = 0; rt < 4; ++rt)
#pragma unroll
    for (int ct = 0; ct < 4; ++ct) acc[rt][ct] = (f32x4){0.f, 0.f, 0.f, 0.f};
  short8 az = {0, 0, 0, 0, 0, 0, 0, 0};

#pragma unroll
  for (int s = 0; s < 4; ++s) {
    int koff = s * 32 + quad * 8;
    short8 a[4];
#pragma unroll
    for (int rt = 0; rt < 4; ++rt) {
      int row = mw + rt * 16 + lm;
      a[rt] = (row < N_NODES)
                  ? *reinterpret_cast<const short8*>(h + (size_t)row * 128 + koff)
                  : az;
    }
#pragma unroll
    for (int ct = 0; ct < 4; ++ct) {
      short8 b = wl8[(s * 8 + tgb + ct) * 64 + lane];
#pragma unroll
      for (int rt = 0; rt < 4; ++rt)
        acc[rt][ct] =
            __builtin_amdgcn_mfma_f32_16x16x32_bf16(a[rt], b, acc[rt][ct], 0, 0, 0);
    }
  }

  if ((w & 1) == 0) {  // cols 0..63 -> hw = h@Wn1 (bf16)
#pragma unroll
    for (int rt = 0; rt < 4; ++rt)
#pragma unroll
      for (int ct = 0; ct < 4; ++ct)
#pragma unroll
        for (int i = 0; i < 4; ++i) {
          int row = mw + rt * 16 + quad * 4 + i;
          if (row < N_NODES)
            hw[(size_t)row * 64 + ct * 16 + lm] = f2bf(acc[rt][ct][i]);
        }
  } else {  // cols 64..127 -> out = h@Ws1 + b1 (f32)
    float bv[4];
#pragma unroll
    for (int ct = 0; ct < 4; ++ct) bv[ct] = b1[ct * 16 + lm];
#pragma unroll
    for (int rt = 0; rt < 4; ++rt)
#pragma unroll
      for (int ct = 0; ct < 4; ++ct)
#pragma unroll
        for (int i = 0; i < 4; ++i) {
          int row = mw + rt * 16 + quad * 4 + i;
          if (row < N_NODES)
            out[(size_t)row * 64 + ct * 16 + lm] = acc[rt][ct][i] + bv[ct];
        }
  }
}

// ---------------- layer-1 aggregation: out[n] += mean(hw[src]) -------------
// Eighth-wave per 128B row (8 lanes x uint4), unroll x2 -> 16 edges per
// wave iteration, 2 x 16B loads in flight per lane.
__global__ __launch_bounds__(256) void k_agg1(
    const uint4* __restrict__ hw4, const int* __restrict__ cnt,
    const int* __restrict__ bucket, const int* __restrict__ ovf_cnt,
    const int* __restrict__ ovf, float* __restrict__ out) {
  int n = blockIdx.x * 4 + (threadIdx.x >> 6);
  int lane = threadIdx.x & 63;
  if (n >= N_NODES) return;
  int g = lane >> 3;   // 0..7: edge slot
  int li = lane & 7;   // 16B chunk within the 128B row
  int c = cnt[n];
  int kb = min(c, CAP);
  int id = (lane < kb) ? bucket[(size_t)n * CAP + lane] : 0;
  float acc[8] = {0.f, 0.f, 0.f, 0.f, 0.f, 0.f, 0.f, 0.f};
  int j = 0;
  for (; j + 16 <= kb; j += 16) {
    int s0 = __shfl(id, j + g, 64);
    int s1 = __shfl(id, j + 8 + g, 64);
    uint4 u0 = hw4[(size_t)s0 * 8 + li];
    uint4 u1 = hw4[(size_t)s1 * 8 + li];
    ACC8(u0);
    ACC8(u1);
  }
  for (; j < kb; j += 8) {
    int e = j + g;
    int s = __shfl(id, min(e, kb - 1), 64);
    if (e < kb) {
      uint4 u = hw4[(size_t)s * 8 + li];
      ACC8(u);
    }
  }
  // cold overflow path: entry i handled by slot (i&7)
  int oc = min(*ovf_cnt, OVF_CAP);
  for (int i = 0; i < oc; ++i) {
    if ((i & 7) == g && ovf[2 * i + 1] == n) {
      uint4 u = hw4[(size_t)ovf[2 * i] * 8 + li];
      ACC8(u);
    }
  }
#pragma unroll
  for (int k = 0; k < 8; ++k) {
    acc[k] += __shfl_xor(acc[k], 8, 64);
    acc[k] += __shfl_xor(acc[k], 16, 64);
    acc[k] += __shfl_xor(acc[k], 32, 64);
  }
  if (g == 0) {
    float inv = 1.0f / (float)max(c, 1);
    float* op = out + (size_t)n * OUTF + li * 8;
    float4 c0 = *reinterpret_cast<float4*>(op);
    float4 c1 = *reinterpret_cast<float4*>(op + 4);
    c0.x += acc[0] * inv;
    c0.y += acc[1] * inv;
    c0.z += acc[2] * inv;
    c0.w += acc[3] * inv;
    c1.x += acc[4] * inv;
    c1.y += acc[5] * inv;
    c1.z += acc[6] * inv;
    c1.w += acc[7] * inv;
    *reinterpret_cast<float4*>(op) = c0;
    *reinterpret_cast<float4*>(op + 4) = c1;
  }
}

extern "C" void kernel_launch(void* const* d_in, const int* in_sizes, int n_in,
                              void* d_out, int out_size, void* d_ws,
                              size_t ws_size, hipStream_t stream) {
  const float* feat = (const float*)d_in[0];
  const int* src = (const int*)d_in[1];
  const int* dst = (const int*)d_in[2];
  const float* Ws0 = (const float*)d_in[3];
  const float* Wn0 = (const float*)d_in[4];
  const float* b0 = (const float*)d_in[5];
  const float* Ws1 = (const float*)d_in[6];
  const float* Wn1 = (const float*)d_in[7];
  const float* b1 = (const float*)d_in[8];
  char* ws = (char*)d_ws;

  // Workspace (74.17 MB <= 77.2 MB proven):
  //   hbuf    @ 0          : 25,600,000  (phase1: binbuf 7.2MB; then agg0/h)
  //   cnt     @ 25,600,000 :    400,000
  //   ovf_cnt @ 26,000,000 :         64
  //   gcursor @ 26,000,064 :      1,600  (391 bin cursors)
  //   ovf     @ 26,001,664 :     65,536
  //   bucket  @ 26,067,200 : 22,400,000  (CAP=56)
  //   feat_bf @ 48,467,200 : 25,600,000  (bf16; hw reuses after gemm0)
  //   wp0     @ 74,067,200 :     65,536
  //   wp1     @ 74,132,736 :     32,768
  ushort* hbuf = (ushort*)(ws);
  uint* binbuf = (uint*)(ws);  // lives in hbuf region until k_scat done
  int* cnt = (int*)(ws + 25600000);
  int* ovf_cnt = (int*)(ws + 26000000);
  uint* gcursor = (uint*)(ws + 26000064);
  int* ovf = (int*)(ws + 26001664);
  int* bucket = (int*)(ws + 26067200);
  ushort* fbf = (ushort*)(ws + 48467200);
  ushort* hw = (ushort*)(ws + 48467200);  // reuses feat_bf post-gemm0
  ushort* wp0 = (ushort*)(ws + 74067200);
  ushort* wp1 = (ushort*)(ws + 74132736);
  float* out = (float*)d_out;

  hipMemsetAsync(ws + 25600000, 0, 467200, stream);  // cnt+ovf_cnt+gcursor+ovf
  k_prep<<<25192, 256, 0, stream>>>(feat, Ws0, Wn0, Ws1, Wn1, (uint*)fbf, wp0,
                                    wp1);
  k_bin<<<782, 512, 0, stream>>>(src, dst, gcursor, binbuf, ovf_cnt, ovf, cnt);
  k_scat<<<BINS, 256, 0, stream>>>(binbuf, gcursor, bucket, cnt, ovf_cnt, ovf);
  k_agg0<<<N_NODES / 4, 256, 0, stream>>>((const uint4*)fbf, cnt, bucket,
                                          ovf_cnt, ovf, (uint4*)hbuf);
  k_gemm0<<<GBLK, 256, 0, stream>>>(fbf, hbuf, (const uint4*)wp0, b0, hbuf);
  k_gemm1<<<GBLK, 256, 0, stream>>>(hbuf, (const uint4*)wp1, b1, hw, out);
  k_agg1<<<N_NODES / 4, 256, 0, stream>>>((const uint4*)hw, cnt, bucket,
                                          ovf_cnt, ovf, out);
}

// Round 8
// 297.365 us; speedup vs baseline: 8.0591x; 1.0092x over previous
//
#include <hip/hip_runtime.h>

#define N_NODES 100000
#define N_EDGES 1600000
#define CAP 56         // per-node bucket capacity (Poisson(16): P(deg>56)~1e-14)
#define OVF_CAP 8192
#define GBLK 782       // ceil(100000/128) gemm blocks; also bin blocks (2048 edges)
#define BINS 391       // ceil(100000/256): bin = dst>>8
#define BINCAP 4608    // Poisson(4096) + 8 sigma
#define ABLK 1563      // ceil(100000/64) agg blocks (64 nodes each)

typedef unsigned int uint;
typedef unsigned short ushort;
typedef __attribute__((ext_vector_type(8))) short short8;  // 8 bf16 (4 VGPRs)
typedef __attribute__((ext_vector_type(4))) float f32x4;   // 4 fp32

__device__ __forceinline__ ushort f2bf(float f) {
  uint x = __float_as_uint(f);
  x += 0x7fffu + ((x >> 16) & 1u);  // round-to-nearest-even
  return (ushort)(x >> 16);
}
__device__ __forceinline__ float bflo(uint u) {
  return __uint_as_float(u << 16);
}
__device__ __forceinline__ float bfhi(uint u) {
  return __uint_as_float(u & 0xffff0000u);
}
// low/high 4 floats of a uint4 (8 bf16)
__device__ __forceinline__ f32x4 uplo(uint4 u) {
  return (f32x4){bflo(u.x), bfhi(u.x), bflo(u.y), bfhi(u.y)};
}
__device__ __forceinline__ f32x4 uphi(uint4 u) {
  return (f32x4){bflo(u.z), bfhi(u.z), bflo(u.w), bfhi(u.w)};
}

// ---------------- fused: edge binning + feat cvt + weight packing ----------
// Blocks [0,782): bin 2048 edges each into dense per-bin segments (LDS
// histogram -> ~391 global atomics -> packed (src | dlow<<17) writes).
// Blocks [782,25782): feat f32->bf16. Rest: MFMA B-frag weight packing.
// Bin blocks FIRST so the latency-bound binning overlaps BW-bound cvt.
__global__ __launch_bounds__(256) void k_pb(
    const int* __restrict__ src, const int* __restrict__ dst,
    const float* __restrict__ feat, const float* __restrict__ Ws0,
    const float* __restrict__ Wn0, const float* __restrict__ Ws1,
    const float* __restrict__ Wn1, uint* __restrict__ gcursor,
    uint* __restrict__ binbuf, int* __restrict__ ovf_cnt,
    int* __restrict__ ovf, uint* __restrict__ fbfu, ushort* __restrict__ wp0,
    ushort* __restrict__ wp1) {
  __shared__ uint hist[BINS];
  __shared__ uint base[BINS];
  int b = blockIdx.x;
  int tid = threadIdx.x;
  if (b < GBLK) {
    for (int i = tid; i < BINS; i += 256) hist[i] = 0;
    __syncthreads();
    int e0 = b * 2048;
    uint val[8], bn[8], rk[8];
    int vld[8];
#pragma unroll
    for (int it = 0; it < 8; ++it) {
      int e = e0 + it * 256 + tid;
      vld[it] = (e < N_EDGES);
      if (vld[it]) {
        uint s = (uint)src[e];
        uint d = (uint)dst[e];
        bn[it] = d >> 8;
        rk[it] = atomicAdd(&hist[bn[it]], 1u);
        val[it] = s | ((d & 255u) << 17);
      }
    }
    __syncthreads();
    for (int i = tid; i < BINS; i += 256)
      base[i] = hist[i] ? atomicAdd(&gcursor[i], hist[i]) : 0u;
    __syncthreads();
#pragma unroll
    for (int it = 0; it < 8; ++it) {
      if (!vld[it]) continue;
      uint p = base[bn[it]] + rk[it];
      if (p < BINCAP) {
        binbuf[(size_t)bn[it] * BINCAP + p] = val[it];
      } else {  // ~never: segment overflow -> ovf, NOT counted (bit30=0)
        int o = atomicAdd(ovf_cnt, 1);
        if (o < OVF_CAP) {
          ovf[2 * o] = (int)(val[it] & 0x1FFFFu);
          ovf[2 * o + 1] = (int)(bn[it] * 256 + (val[it] >> 17));
        }
      }
    }
    return;
  }
  if (b < GBLK + 25000) {  // feat conversion: N*64 uint outputs
    int i = (b - GBLK) * 256 + tid;
    float2 v = reinterpret_cast<const float2*>(feat)[i];
    fbfu[i] = (uint)f2bf(v.x) | ((uint)f2bf(v.y) << 16);
    return;
  }
  // B-frag layout (16x16x32 bf16): lane = 16q+c holds B[k=8q+j][n=16t+c].
  int idx = (b - GBLK - 25000) * 256 + tid;  // 49152 = 32768 + 16384
  if (idx < 32768) {
    int k = idx >> 7, n = idx & 127;
    float v = (k < 128) ? Ws0[k * 128 + n] : Wn0[(k - 128) * 128 + n];
    int s = k >> 5, q = (k >> 3) & 3, j = k & 7;
    int t = n >> 4, c = n & 15;
    wp0[(((s * 8 + t) * 64) + (q * 16 + c)) * 8 + j] = f2bf(v);
  } else {
    int i2 = idx - 32768;
    int k = i2 >> 7, n = i2 & 127;
    float v = (n < 64) ? Wn1[k * 64 + n] : Ws1[k * 64 + (n - 64)];
    int s = k >> 5, q = (k >> 3) & 3, j = k & 7;
    int t = n >> 4, c = n & 15;
    wp1[(((s * 8 + t) * 64) + (q * 16 + c)) * 8 + j] = f2bf(v);
  }
}

// ---------------- layer-0 aggregation (LDS bucket): 64 nodes/block ---------
// Phase 1: scan own quarter-bin's binbuf segment, scatter src ids into a
// 14.3KB LDS bucket (LDS atomics, no global bucket traffic, no cnt array).
// Phase 2: 16 lanes per node own the full 256B row; branchless 8-edge main
// loop (cndmask'd srcs, mask-FMA accumulate -> v_pk_fma_f32); no reductions.
__global__ __launch_bounds__(256) void k_agg0(
    const uint4* __restrict__ fbf4, const uint* __restrict__ binbuf,
    const uint* __restrict__ gcursor, int* __restrict__ ovf_cnt,
    int* __restrict__ ovf, uint4* __restrict__ agg4) {
  __shared__ __attribute__((aligned(16))) int lbkt[64 * CAP];
  __shared__ uint lcnt[64];
  int bb = blockIdx.x;
  int tid = threadIdx.x;
  if (tid < 64) lcnt[tid] = 0;
  __syncthreads();
  int bin = bb >> 2, q2 = bb & 3;
  int ne = min((int)gcursor[bin], BINCAP);
  for (int i = tid; i < ne; i += 256) {
    uint v = binbuf[(size_t)bin * BINCAP + i];
    uint dl = v >> 17;
    if ((int)(dl >> 6) == q2) {
      int ldl = (int)(dl & 63u);
      uint pos = atomicAdd(&lcnt[ldl], 1u);
      if (pos < CAP) {
        lbkt[ldl * CAP + pos] = (int)(v & 0x1FFFFu);
      } else {  // ~never: bucket spill -> ovf, already counted (bit30=1)
        int o = atomicAdd(ovf_cnt, 1);
        if (o < OVF_CAP) {
          ovf[2 * o] = (int)(v & 0x1FFFFu);
          ovf[2 * o + 1] = (bin * 256 + (int)dl) | (1 << 30);
        }
      }
    }
  }
  __syncthreads();
  int g = tid >> 4, li = tid & 15;
  const int4* lb4 = reinterpret_cast<const int4*>(lbkt);
  int oc = min(*ovf_cnt, OVF_CAP);
#pragma unroll
  for (int p = 0; p < 4; ++p) {
    int nl = p * 16 + g;
    int n = bb * 64 + nl;
    int c = (int)lcnt[nl];
    int kb = min(c, CAP);
    f32x4 accA = (f32x4){0.f, 0.f, 0.f, 0.f};
    f32x4 accB = (f32x4){0.f, 0.f, 0.f, 0.f};
    for (int j = 0; j < kb; j += 8) {
      int4 ia = lb4[nl * 14 + (j >> 2)];
      int4 ib = lb4[nl * 14 + (j >> 2) + 1];
      int s0 = ia.x;
      int s1 = (j + 1 < kb) ? ia.y : 0;
      int s2 = (j + 2 < kb) ? ia.z : 0;
      int s3 = (j + 3 < kb) ? ia.w : 0;
      int s4 = (j + 4 < kb) ? ib.x : 0;
      int s5 = (j + 5 < kb) ? ib.y : 0;
      int s6 = (j + 6 < kb) ? ib.z : 0;
      int s7 = (j + 7 < kb) ? ib.w : 0;
      uint4 u0 = fbf4[(size_t)s0 * 16 + li];
      uint4 u1 = fbf4[(size_t)s1 * 16 + li];
      uint4 u2 = fbf4[(size_t)s2 * 16 + li];
      uint4 u3 = fbf4[(size_t)s3 * 16 + li];
      uint4 u4 = fbf4[(size_t)s4 * 16 + li];
      uint4 u5 = fbf4[(size_t)s5 * 16 + li];
      uint4 u6 = fbf4[(size_t)s6 * 16 + li];
      uint4 u7 = fbf4[(size_t)s7 * 16 + li];
      float m1 = (j + 1 < kb) ? 1.f : 0.f;
      float m2 = (j + 2 < kb) ? 1.f : 0.f;
      float m3 = (j + 3 < kb) ? 1.f : 0.f;
      float m4 = (j + 4 < kb) ? 1.f : 0.f;
      float m5 = (j + 5 < kb) ? 1.f : 0.f;
      float m6 = (j + 6 < kb) ? 1.f : 0.f;
      float m7 = (j + 7 < kb) ? 1.f : 0.f;
      accA += uplo(u0);      accB += uphi(u0);
      accA += uplo(u1) * m1; accB += uphi(u1) * m1;
      accA += uplo(u2) * m2; accB += uphi(u2) * m2;
      accA += uplo(u3) * m3; accB += uphi(u3) * m3;
      accA += uplo(u4) * m4; accB += uphi(u4) * m4;
      accA += uplo(u5) * m5; accB += uphi(u5) * m5;
      accA += uplo(u6) * m6; accB += uphi(u6) * m6;
      accA += uplo(u7) * m7; accB += uphi(u7) * m7;
    }
    for (int i = 0; i < oc; ++i) {  // cold fallback path
      int df = ovf[2 * i + 1];
      if ((df & 0x1FFFF) == n) {
        uint4 u = fbf4[(size_t)ovf[2 * i] * 16 + li];
        accA += uplo(u);
        accB += uphi(u);
        c += ((df >> 30) & 1) ^ 1;
      }
    }
    float inv = 1.f / (float)max(c, 1);
    accA *= inv;
    accB *= inv;
    if (n < N_NODES) {
      uint4 o;
      o.x = (uint)f2bf(accA.x) | ((uint)f2bf(accA.y) << 16);
      o.y = (uint)f2bf(accA.z) | ((uint)f2bf(accA.w) << 16);
      o.z = (uint)f2bf(accB.x) | ((uint)f2bf(accB.y) << 16);
      o.w = (uint)f2bf(accB.z) | ((uint)f2bf(accB.w) << 16);
      agg4[(size_t)n * 16 + li] = o;
    }
  }
}

// ---------------- layer-0 MFMA GEMM: h = relu([feat|agg] @ Wp0 + b0) -------
// 128x128/block, 4 waves; wave = 64x64 = 4x4 C-frags; K=256 = 8 steps.
// aggb and h ALIAS (block reads own rows, overwrites post-barrier).
__global__ __launch_bounds__(256) void k_gemm0(
    const ushort* __restrict__ fbf, const ushort* aggb,
    const uint4* __restrict__ wp0g, const float* __restrict__ b0,
    ushort* h) {
  __shared__ uint4 wlds[4096];  // 64KB
  int tid = threadIdx.x;
#pragma unroll
  for (int i = 0; i < 16; ++i) wlds[i * 256 + tid] = wp0g[i * 256 + tid];
  __syncthreads();
  const short8* wl8 = reinterpret_cast<const short8*>(wlds);

  int lane = tid & 63, w = tid >> 6;
  int quad = lane >> 4, lm = lane & 15;
  int mw = blockIdx.x * 128 + (w >> 1) * 64;
  int tgb = (w & 1) * 4;

  f32x4 acc[4][4];
#pragma unroll
  for (int rt = 0; rt < 4; ++rt)
#pragma unroll
    for (int ct = 0; ct < 4; ++ct) acc[rt][ct] = (f32x4){0.f, 0.f, 0.f, 0.f};
  short8 az = {0, 0, 0, 0, 0, 0, 0, 0};

#pragma unroll
  for (int s = 0; s < 8; ++s) {
    const ushort* bsrc = (s < 4) ? fbf : aggb;
    int koff = (s & 3) * 32 + quad * 8;
    short8 a[4];
#pragma unroll
    for (int rt = 0; rt < 4; ++rt) {
      int row = mw + rt * 16 + lm;
      a[rt] = (row < N_NODES)
                  ? *reinterpret_cast<const short8*>(bsrc + (size_t)row * 128 + koff)
                  : az;
    }
#pragma unroll
    for (int ct = 0; ct < 4; ++ct) {
      short8 b = wl8[(s * 8 + tgb + ct) * 64 + lane];
#pragma unroll
      for (int rt = 0; rt < 4; ++rt)
        acc[rt][ct] =
            __builtin_amdgcn_mfma_f32_16x16x32_bf16(a[rt], b, acc[rt][ct], 0, 0, 0);
    }
  }

  __syncthreads();  // all waves done reading aggb before h overwrites
  float bv[4];
#pragma unroll
  for (int ct = 0; ct < 4; ++ct) bv[ct] = b0[(tgb + ct) * 16 + lm];
#pragma unroll
  for (int rt = 0; rt < 4; ++rt)
#pragma unroll
    for (int ct = 0; ct < 4; ++ct)
#pragma unroll
      for (int i = 0; i < 4; ++i) {
        int row = mw + rt * 16 + quad * 4 + i;
        if (row < N_NODES) {
          int col = (tgb + ct) * 16 + lm;
          h[(size_t)row * 128 + col] = f2bf(fmaxf(acc[rt][ct][i] + bv[ct], 0.f));
        }
      }
}

// ---------------- fused layer-1 MFMA GEMM: [hw | sout] = h @ Wp1 -----------
__global__ __launch_bounds__(256) void k_gemm1(
    const ushort* __restrict__ h, const uint4* __restrict__ wp1g,
    const float* __restrict__ b1, ushort* __restrict__ hw,
    float* __restrict__ out) {
  __shared__ uint4 wlds[2048];  // 32KB
  int tid = threadIdx.x;
#pragma unroll
  for (int i = 0; i < 8; ++i) wlds[i * 256 + tid] = wp1g[i * 256 + tid];
  __syncthreads();
  const short8* wl8 = reinterpret_cast<const short8*>(wlds);

  int lane = tid & 63, w = tid >> 6;
  int quad = lane >> 4, lm = lane & 15;
  int mw = blockIdx.x * 128 + (w >> 1) * 64;
  int tgb = (w & 1) * 4;

  f32x4 acc[4][4];
#pragma unroll
  for (int rt = 0; rt < 4; ++rt)
#pragma unroll
    for (int ct = 0; ct < 4; ++ct) acc[rt][ct] = (f32x4){0.f, 0.f, 0.f, 0.f};
  short8 az = {0, 0, 0, 0, 0, 0, 0, 0};

#pragma unroll
  for (int s = 0; s < 4; ++s) {
    int koff = s * 32 + quad * 8;
    short8 a[4];
#pragma unroll
    for (int rt = 0; rt < 4; ++rt) {
      int row = mw + rt * 16 + lm;
      a[rt] = (row < N_NODES)
                  ? *reinterpret_cast<const short8*>(h + (size_t)row * 128 + koff)
                  : az;
    }
#pragma unroll
    for (int ct = 0; ct < 4; ++ct) {
      short8 b = wl8[(s * 8 + tgb + ct) * 64 + lane];
#pragma unroll
      for (int rt = 0; rt < 4; ++rt)
        acc[rt][ct] =
            __builtin_amdgcn_mfma_f32_16x16x32_bf16(a[rt], b, acc[rt][ct], 0, 0, 0);
    }
  }

  if ((w & 1) == 0) {  // cols 0..63 -> hw = h@Wn1 (bf16)
#pragma unroll
    for (int rt = 0; rt < 4; ++rt)
#pragma unroll
      for (int ct = 0; ct < 4; ++ct)
#pragma unroll
        for (int i = 0; i < 4; ++i) {
          int row = mw + rt * 16 + quad * 4 + i;
          if (row < N_NODES)
            hw[(size_t)row * 64 + ct * 16 + lm] = f2bf(acc[rt][ct][i]);
        }
  } else {  // cols 64..127 -> out = h@Ws1 + b1 (f32)
    float bv[4];
#pragma unroll
    for (int ct = 0; ct < 4; ++ct) bv[ct] = b1[ct * 16 + lm];
#pragma unroll
    for (int rt = 0; rt < 4; ++rt)
#pragma unroll
      for (int ct = 0; ct < 4; ++ct)
#pragma unroll
        for (int i = 0; i < 4; ++i) {
          int row = mw + rt * 16 + quad * 4 + i;
          if (row < N_NODES)
            out[(size_t)row * 64 + ct * 16 + lm] = acc[rt][ct][i] + bv[ct];
        }
  }
}

// ---------------- layer-1 aggregation (LDS bucket): out[n] += mean ---------
// Same structure as k_agg0; 8 lanes per node own the 128B hw row.
__global__ __launch_bounds__(256) void k_agg1(
    const uint4* __restrict__ hw4, const uint* __restrict__ binbuf,
    const uint* __restrict__ gcursor, int* __restrict__ ovf_cnt,
    int* __restrict__ ovf, float* __restrict__ out) {
  __shared__ __attribute__((aligned(16))) int lbkt[64 * CAP];
  __shared__ uint lcnt[64];
  int bb = blockIdx.x;
  int tid = threadIdx.x;
  if (tid < 64) lcnt[tid] = 0;
  __syncthreads();
  int bin = bb >> 2, q2 = bb & 3;
  int ne = min((int)gcursor[bin], BINCAP);
  for (int i = tid; i < ne; i += 256) {
    uint v = binbuf[(size_t)bin * BINCAP + i];
    uint dl = v >> 17;
    if ((int)(dl >> 6) == q2) {
      int ldl = (int)(dl & 63u);
      uint pos = atomicAdd(&lcnt[ldl], 1u);
      if (pos < CAP) lbkt[ldl * CAP + pos] = (int)(v & 0x1FFFFu);
      // bucket spill already recorded in ovf by k_agg0's pass (bit30=1)
    }
  }
  __syncthreads();
  int g = tid >> 3, li = tid & 7;
  const int4* lb4 = reinterpret_cast<const int4*>(lbkt);
  int oc = min(*ovf_cnt, OVF_CAP);
#pragma unroll
  for (int p = 0; p < 2; ++p) {
    int nl = p * 32 + g;
    int n = bb * 64 + nl;
    int c = (int)lcnt[nl];
    int kb = min(c, CAP);
    f32x4 accA = (f32x4){0.f, 0.f, 0.f, 0.f};
    f32x4 accB = (f32x4){0.f, 0.f, 0.f, 0.f};
    for (int j = 0; j < kb; j += 8) {
      int4 ia = lb4[nl * 14 + (j >> 2)];
      int4 ib = lb4[nl * 14 + (j >> 2) + 1];
      int s0 = ia.x;
      int s1 = (j + 1 < kb) ? ia.y : 0;
      int s2 = (j + 2 < kb) ? ia.z : 0;
      int s3 = (j + 3 < kb) ? ia.w : 0;
      int s4 = (j + 4 < kb) ? ib.x : 0;
      int s5 = (j + 5 < kb) ? ib.y : 0;
      int s6 = (j + 6 < kb) ? ib.z : 0;
      int s7 = (j + 7 < kb) ? ib.w : 0;
      uint4 u0 = hw4[(size_t)s0 * 8 + li];
      uint4 u1 = hw4[(size_t)s1 * 8 + li];
      uint4 u2 = hw4[(size_t)s2 * 8 + li];
      uint4 u3 = hw4[(size_t)s3 * 8 + li];
      uint4 u4 = hw4[(size_t)s4 * 8 + li];
      uint4 u5 = hw4[(size_t)s5 * 8 + li];
      uint4 u6 = hw4[(size_t)s6 * 8 + li];
      uint4 u7 = hw4[(size_t)s7 * 8 + li];
      float m1 = (j + 1 < kb) ? 1.f : 0.f;
      float m2 = (j + 2 < kb) ? 1.f : 0.f;
      float m3 = (j + 3 < kb) ? 1.f : 0.f;
      float m4 = (j + 4 < kb) ? 1.f : 0.f;
      float m5 = (j + 5 < kb) ? 1.f : 0.f;
      float m6 = (j + 6 < kb) ? 1.f : 0.f;
      float m7 = (j + 7 < kb) ? 1.f : 0.f;
      accA += uplo(u0);      accB += uphi(u0);
      accA += uplo(u1) * m1; accB += uphi(u1) * m1;
      accA += uplo(u2) * m2; accB += uphi(u2) * m2;
      accA += uplo(u3) * m3; accB += uphi(u3) * m3;
      accA += uplo(u4) * m4; accB += uphi(u4) * m4;
      accA += uplo(u5) * m5; accB += uphi(u5) * m5;
      accA += uplo(u6) * m6; accB += uphi(u6) * m6;
      accA += uplo(u7) * m7; accB += uphi(u7) * m7;
    }
    for (int i = 0; i < oc; ++i) {  // cold fallback path
      int df = ovf[2 * i + 1];
      if ((df & 0x1FFFF) == n) {
        uint4 u = hw4[(size_t)ovf[2 * i] * 8 + li];
        accA += uplo(u);
        accB += uphi(u);
        c += ((df >> 30) & 1) ^ 1;
      }
    }
    if (n < N_NODES) {
      float inv = 1.f / (float)max(c, 1);
      float* op = out + (size_t)n * 64 + li * 8;
      float4 c0 = *reinterpret_cast<float4*>(op);
      float4 c1 = *reinterpret_cast<float4*>(op + 4);
      c0.x += accA.x * inv;
      c0.y += accA.y * inv;
      c0.z += accA.z * inv;
      c0.w += accA.w * inv;
      c1.x += accB.x * inv;
      c1.y += accB.y * inv;
      c1.z += accB.z * inv;
      c1.w += accB.w * inv;
      *reinterpret_cast<float4*>(op) = c0;
      *reinterpret_cast<float4*>(op + 4) = c1;
    }
  }
}

extern "C" void kernel_launch(void* const* d_in, const int* in_sizes, int n_in,
                              void* d_out, int out_size, void* d_ws,
                              size_t ws_size, hipStream_t stream) {
  const float* feat = (const float*)d_in[0];
  const int* src = (const int*)d_in[1];
  const int* dst = (const int*)d_in[2];
  const float* Ws0 = (const float*)d_in[3];
  const float* Wn0 = (const float*)d_in[4];
  const float* b0 = (const float*)d_in[5];
  const float* Ws1 = (const float*)d_in[6];
  const float* Wn1 = (const float*)d_in[7];
  const float* b1 = (const float*)d_in[8];
  char* ws = (char*)d_ws;

  // Workspace (74.17 MB <= 77.2 MB proven):
  //   hbuf    @ 0          : 25,600,000  (bf16 agg0, then h)
  //   ovf_cnt @ 25,600,000 :         64
  //   gcursor @ 25,600,064 :      1,600  (391 bin cursors)
  //   ovf     @ 25,601,664 :     65,536
  //   binbuf  @ 26,067,200 :  7,206,912  (391 x 4608 packed edges)
  //   feat_bf @ 48,467,200 : 25,600,000  (bf16; hw reuses after gemm0)
  //   wp0     @ 74,067,200 :     65,536
  //   wp1     @ 74,132,736 :     32,768
  ushort* hbuf = (ushort*)(ws);
  int* ovf_cnt = (int*)(ws + 25600000);
  uint* gcursor = (uint*)(ws + 25600064);
  int* ovf = (int*)(ws + 25601664);
  uint* binbuf = (uint*)(ws + 26067200);
  ushort* fbf = (ushort*)(ws + 48467200);
  ushort* hw = (ushort*)(ws + 48467200);  // reuses feat_bf post-gemm0
  ushort* wp0 = (ushort*)(ws + 74067200);
  ushort* wp1 = (ushort*)(ws + 74132736);
  float* out = (float*)d_out;

  hipMemsetAsync(ws + 25600000, 0, 1664, stream);  // ovf_cnt + gcursor
  k_pb<<<GBLK + 25000 + 192, 256, 0, stream>>>(src, dst, feat, Ws0, Wn0, Ws1,
                                               Wn1, gcursor, binbuf, ovf_cnt,
                                               ovf, (uint*)fbf, wp0, wp1);
  k_agg0<<<ABLK, 256, 0, stream>>>((const uint4*)fbf, binbuf, gcursor, ovf_cnt,
                                   ovf, (uint4*)hbuf);
  k_gemm0<<<GBLK, 256, 0, stream>>>(fbf, hbuf, (const uint4*)wp0, b0, hbuf);
  k_gemm1<<<GBLK, 256, 0, stream>>>(hbuf, (const uint4*)wp1, b1, hw, out);
  k_agg1<<<ABLK, 256, 0, stream>>>((const uint4*)hw, binbuf, gcursor, ovf_cnt,
                                   ovf, out);
}